// Round 13
// baseline (465.320 us; speedup 1.0000x reference)
//
#include <hip/hip_runtime.h>
#include <hip/hip_bf16.h>

// ---------------------------------------------------------------------------
// FactorizedAttentionBlock (TimeSformer divided space-time attention)
// DIM=768, NH=12, HD=64, HID=1152(pad 1280), B=8, T=8, HW=196, N=197, BT=64
// FP32 in/out. bf16 MFMA GEMMs + MFMA flash attention. fp32 residual in d_out.
// R13: R11 base (best, 376us) + split-K=2 for the two low-fill N=768 GEMMs
//      (proj, fc2): 150 -> 300 blocks, halves atomicAdd fp32 into residual,
//      bias applied by half 0 only. GEMM inner schedule = R7/R11 (empirical
//      minimum across 6 variants at this shape).
// ---------------------------------------------------------------------------

#define DIM   768
#define NH    12
#define HD    64
#define HID   1152
#define HIDP  1280
#define B_    8
#define T_    8
#define HW_   196
#define NTOK  197
#define BT_   64
#define MROWS (BT_ * NTOK)        // 12608
#define TROWS (B_ * HW_ * T_)     // 12544

typedef __bf16 bf16x8 __attribute__((ext_vector_type(8)));
typedef float  f32x4  __attribute__((ext_vector_type(4)));

__device__ inline float bf2f(ushort u) { return __uint_as_float(((unsigned)u) << 16); }
__device__ inline ushort f2bf(float f) {
    unsigned u = __float_as_uint(f);
    unsigned r = (u + 0x7fffu + ((u >> 16) & 1u)) >> 16;
    return (ushort)r;
}

__device__ inline float wred_sum(float v) {
    #pragma unroll
    for (int m = 32; m; m >>= 1) v += __shfl_xor(v, m);
    return v;
}

__device__ __forceinline__ void gload_lds16(const void* g, void* l) {
    __builtin_amdgcn_global_load_lds(
        (const __attribute__((address_space(1))) unsigned int*)g,
        (__attribute__((address_space(3))) unsigned int*)l, 16, 0, 0);
}

// XCD-bijective remap (m204)
__device__ __forceinline__ int xcd_lin(int gid, int nwg) {
    int q = nwg >> 3, r = nwg & 7;
    int xcd = gid & 7, idx = gid >> 3;
    return (xcd < r ? xcd * (q + 1) : r * (q + 1) + (xcd - r) * q) + idx;
}

#define MFMA16(a, b, c) __builtin_amdgcn_mfma_f32_16x16x32_bf16(a, b, c, 0, 0, 0)

// ---------------------------------------------------------------------------
// prep: single fused prep kernel, block-range dispatch.
// ---------------------------------------------------------------------------
#define PREP_T0 576
#define PREP_T1 (PREP_T0 + 192)
#define PREP_T2 (PREP_T1 + TROWS / 4)
#define FL_DD8  73728
#define FL_C0   (3 * FL_DD8)              // qkv
#define FL_C1   (FL_C0 + FL_DD8)          // proj
#define FL_C2   (FL_C1 + 3 * FL_DD8)      // tqkv
#define FL_C3   (FL_C2 + FL_DD8)          // tfc
#define FL_C4   (FL_C3 + HID * DIM / 8)   // fc1 rows
#define FL_C5   (FL_C4 + (HIDP - HID) * DIM / 8)  // fc1 pad rows
#define FL_C6   (FL_C5 + DIM * HIDP / 8)  // fc2 padded
#define FL_C7   (FL_C6 + HIDP / 8)        // fc1 bias pad
#define FL_C8   (FL_C7 + BT_ * DIM / 8)   // init_cls
#define PREP_GRID (PREP_T2 + (FL_C8 + 255) / 256)

__global__ __launch_bounds__(256) void prep(
    const float* __restrict__ x, const float* __restrict__ tln_g, const float* __restrict__ tln_b,
    const float* __restrict__ qkv_w, const float* __restrict__ proj_w,
    const float* __restrict__ tqkv_w, const float* __restrict__ tproj_w,
    const float* __restrict__ tproj_b, const float* __restrict__ tfc_wf,
    const float* __restrict__ tfc_b, const float* __restrict__ fc1_w,
    const float* __restrict__ fc1_b, const float* __restrict__ fc2_w,
    ushort* __restrict__ w_qkv, ushort* __restrict__ w_proj,
    ushort* __restrict__ w_tqkv, ushort* __restrict__ w_tfc,
    ushort* __restrict__ tprojT, ushort* __restrict__ w_fc1p,
    ushort* __restrict__ w_fc2p, float* __restrict__ fc1_bp,
    float* __restrict__ b_comb, ushort* __restrict__ bufA, float* __restrict__ out)
{
    __shared__ float tsm[32][33];
    int b = blockIdx.x, tid = threadIdx.x;

    if (b < PREP_T0) {             // ---- tproj transpose+cast
        int bx = b % 24, by = b / 24;
        int lx = tid & 31, ly = tid >> 5;
        #pragma unroll
        for (int i = 0; i < 32; i += 8)
            tsm[ly + i][lx] = tproj_w[(size_t)(by * 32 + ly + i) * DIM + bx * 32 + lx];
        __syncthreads();
        #pragma unroll
        for (int i = 0; i < 32; i += 8)
            tprojT[(size_t)(bx * 32 + ly + i) * DIM + by * 32 + lx] = f2bf(tsm[lx][ly + i]);
        return;
    }
    if (b < PREP_T1) {             // ---- b_comb
        int w = (b - PREP_T0) * 4 + (tid >> 6), lane = tid & 63;
        float s = 0.f;
        for (int j = lane; j < DIM; j += 64) s += tfc_wf[(size_t)w * DIM + j] * tproj_b[j];
        s = wred_sum(s);
        if (lane == 0) b_comb[w] = s + tfc_b[w];
        return;
    }
    if (b < PREP_T2) {             // ---- ln_gather -> bufA
        int widx = tid >> 6, lane = tid & 63;
        int r = (b - PREP_T1) * 4 + widx;
        int t = r & 7, pp = (r >> 3) % HW_, bb = r / (HW_ * T_);
        const float* row = x + ((size_t)(bb * T_ + t) * NTOK + 1 + pp) * DIM;
        float v[12], sum = 0.f, sq = 0.f;
        #pragma unroll
        for (int c = 0; c < 3; ++c) {
            float4 t4 = *(const float4*)(row + c * 256 + lane * 4);
            v[c*4+0] = t4.x; v[c*4+1] = t4.y; v[c*4+2] = t4.z; v[c*4+3] = t4.w;
            sum += t4.x + t4.y + t4.z + t4.w;
            sq  += t4.x*t4.x + t4.y*t4.y + t4.z*t4.z + t4.w*t4.w;
        }
        sum = wred_sum(sum); sq = wred_sum(sq);
        float mean = sum * (1.f / DIM);
        float var  = sq * (1.f / DIM) - mean * mean;
        float rstd = rsqrtf(var + 1e-5f);
        #pragma unroll
        for (int c = 0; c < 3; ++c) {
            int idx = c * 256 + lane * 4;
            float4 gg = *(const float4*)(tln_g + idx);
            float4 bb2 = *(const float4*)(tln_b + idx);
            ushort4 o;
            o.x = f2bf((v[c*4+0] - mean) * rstd * gg.x + bb2.x);
            o.y = f2bf((v[c*4+1] - mean) * rstd * gg.y + bb2.y);
            o.z = f2bf((v[c*4+2] - mean) * rstd * gg.z + bb2.z);
            o.w = f2bf((v[c*4+3] - mean) * rstd * gg.w + bb2.w);
            *(ushort4*)(bufA + (size_t)r * DIM + idx) = o;
        }
        return;
    }

    int i = (b - PREP_T2) * 256 + tid;
    if (i >= FL_C8) return;
    if (i < FL_C4) {
        const float* s; ushort* d; int base;
        if      (i < FL_C0) { s = qkv_w;  d = w_qkv;  base = 0;     }
        else if (i < FL_C1) { s = proj_w; d = w_proj; base = FL_C0; }
        else if (i < FL_C2) { s = tqkv_w; d = w_tqkv; base = FL_C1; }
        else if (i < FL_C3) { s = tfc_wf; d = w_tfc;  base = FL_C2; }
        else                { s = fc1_w;  d = w_fc1p; base = FL_C3; }
        int k = i - base;
        float4 a = *(const float4*)(s + (size_t)k * 8);
        float4 bb = *(const float4*)(s + (size_t)k * 8 + 4);
        ushort o[8] = {f2bf(a.x), f2bf(a.y), f2bf(a.z), f2bf(a.w),
                       f2bf(bb.x), f2bf(bb.y), f2bf(bb.z), f2bf(bb.w)};
        *(uint4*)(d + (size_t)k * 8) = *(const uint4*)o;
    } else if (i < FL_C5) {
        int k = i - FL_C4;
        uint4 z = {0u, 0u, 0u, 0u};
        *(uint4*)(w_fc1p + (size_t)HID * DIM + (size_t)k * 8) = z;
    } else if (i < FL_C6) {
        int k = i - FL_C5;
        int r = k / (HIDP / 8), c8 = (k % (HIDP / 8)) * 8;
        ushort o[8];
        if (c8 < HID) {
            const float* s = fc2_w + (size_t)r * HID + c8;
            #pragma unroll
            for (int e = 0; e < 8; ++e) o[e] = f2bf(s[e]);
        } else {
            #pragma unroll
            for (int e = 0; e < 8; ++e) o[e] = 0;
        }
        *(uint4*)(w_fc2p + (size_t)r * HIDP + c8) = *(const uint4*)o;
    } else if (i < FL_C7) {
        int k = (i - FL_C6) * 8;
        #pragma unroll
        for (int e = 0; e < 8; ++e) fc1_bp[k + e] = (k + e < HID) ? fc1_b[k + e] : 0.f;
    } else {
        int k = (i - FL_C7) * 8;
        int r = k / DIM, c = k % DIM;
        size_t off = (size_t)r * NTOK * DIM + c;
        *(float4*)(out + off)     = *(const float4*)(x + off);
        *(float4*)(out + off + 4) = *(const float4*)(x + off + 4);
    }
}

// ---------------------------------------------------------------------------
// gemm256 (R7/R11 schedule): C[M,N] = A[M,K'] @ W[N,K']^T over K' = KK cols
// starting at column offset half*koff (split-K). 256x256, 8 waves (2Mx4N),
// per-wave 128x64. BK=64, dbuf LDS (128KB), 4 phases/K-tile, one
// vmcnt(0)+barrier per K-tile, setprio on MFMA, XOR-swizzled LDS.
// EPI_BIAS_ADD uses atomicAdd (split-K halves race otherwise); bias is
// applied only by half 0. Dual-problem support (blocks >= split -> prob 2).
// ---------------------------------------------------------------------------
enum { EPI_STORE = 0, EPI_BIAS_GELU = 1, EPI_BIAS_ADD = 2, EPI_INIT_TFC = 3 };

template <int KK, int LD, int EPI>
__global__ __launch_bounds__(512, 1) void gemm256(
    const ushort* __restrict__ Ag, const ushort* __restrict__ Wg,
    const float* __restrict__ bias, ushort* __restrict__ Cg,
    const float* __restrict__ xsrc, float* __restrict__ xf,
    int M, int N, int nm, int nn, int grp, int koff,
    const ushort* A2, const ushort* W2, ushort* C2,
    int M2, int N2, int nm2, int nn2, int split)
{
    __shared__ ushort As[2][256 * 64];
    __shared__ ushort Bs[2][256 * 64];

    const int tid  = threadIdx.x;
    const int lane = tid & 63, wid = tid >> 6;
    const int wr = wid >> 2, wc = wid & 3;
    const int fr = lane & 15, fq = lane >> 4;

    int bid = blockIdx.x;
    int half = 0;
    if (bid >= split) {            // problem 2 (W_comb)
        Ag = A2; Wg = W2; Cg = C2; M = M2; N = N2; nm = nm2; nn = nn2;
        bid -= split;
    } else {
        half = bid / (nm * nn);    // split-K half (grid = nm*nn*halves)
        bid -= half * (nm * nn);
    }
    const int kbase = half * koff;

    int lin = xcd_lin(bid, nm * nn);
    int per = grp * nn;
    int g2 = lin / per, rem = lin % per;
    int bm = g2 * grp;
    int gm = nm - bm; if (gm > grp) gm = grp;
    const int m0 = (bm + rem % gm) * 256;
    const int n0 = (rem / gm) * 256;

    const int srow = wid * 8 + (lane >> 3);
    const int scol = 8 * ((lane & 7) ^ (lane >> 3));
    const ushort* aP[4]; const ushort* bP[4];
    #pragma unroll
    for (int j = 0; j < 4; ++j) {
        int ra = m0 + j * 64 + srow; if (ra >= M) ra = M - 1;
        aP[j] = Ag + (size_t)ra * LD + kbase + scol;
        bP[j] = Wg + (size_t)(n0 + j * 64 + srow) * LD + kbase + scol;
    }
    const int ldso = (wid * 8) * 64;

    f32x4 acc[8][4] = {};
    bf16x8 af[4][2], b0[2][2], b1[2][2];

    const int sw0 = (fq * 8) ^ ((fr & 7) * 8);
    const int sw1 = (32 + fq * 8) ^ ((fr & 7) * 8);

    #pragma unroll
    for (int j = 0; j < 4; ++j) gload_lds16(aP[j], &As[0][j * 4096 + ldso]);
    #pragma unroll
    for (int j = 0; j < 4; ++j) gload_lds16(bP[j], &Bs[0][j * 4096 + ldso]);

    constexpr int NT = KK / 64;
    #pragma unroll
    for (int t = 0; t < NT; ++t) {
        const int rb = t & 1, wb = rb ^ 1;
        const bool st = (t + 1 < NT);
        const int kw = (t + 1) * 64;

        asm volatile("s_waitcnt vmcnt(0)" ::: "memory");
        __builtin_amdgcn_s_barrier();
        __builtin_amdgcn_sched_barrier(0);

        // ---- phase 0 ----
        #pragma unroll
        for (int mf = 0; mf < 4; ++mf) {
            af[mf][0] = *(const bf16x8*)&As[rb][(wr * 128 + mf * 16 + fr) * 64 + sw0];
            af[mf][1] = *(const bf16x8*)&As[rb][(wr * 128 + mf * 16 + fr) * 64 + sw1];
        }
        #pragma unroll
        for (int nf = 0; nf < 2; ++nf) {
            b0[nf][0] = *(const bf16x8*)&Bs[rb][(wc * 64 + nf * 16 + fr) * 64 + sw0];
            b0[nf][1] = *(const bf16x8*)&Bs[rb][(wc * 64 + nf * 16 + fr) * 64 + sw1];
        }
        if (st) {
            #pragma unroll
            for (int j = 0; j < 4; ++j) gload_lds16(aP[j] + kw, &As[wb][j * 4096 + ldso]);
        }
        asm volatile("s_waitcnt lgkmcnt(0)" ::: "memory");
        __builtin_amdgcn_sched_barrier(0);
        __builtin_amdgcn_s_setprio(1);
        #pragma unroll
        for (int mf = 0; mf < 4; ++mf)
            #pragma unroll
            for (int nf = 0; nf < 2; ++nf) {
                acc[mf][nf] = MFMA16(af[mf][0], b0[nf][0], acc[mf][nf]);
                acc[mf][nf] = MFMA16(af[mf][1], b0[nf][1], acc[mf][nf]);
            }
        __builtin_amdgcn_s_setprio(0);
        __builtin_amdgcn_sched_barrier(0);

        // ---- phase 1 ----
        #pragma unroll
        for (int nf = 0; nf < 2; ++nf) {
            b1[nf][0] = *(const bf16x8*)&Bs[rb][(wc * 64 + (nf + 2) * 16 + fr) * 64 + sw0];
            b1[nf][1] = *(const bf16x8*)&Bs[rb][(wc * 64 + (nf + 2) * 16 + fr) * 64 + sw1];
        }
        if (st) {
            #pragma unroll
            for (int j = 0; j < 4; ++j) gload_lds16(bP[j] + kw, &Bs[wb][j * 4096 + ldso]);
        }
        asm volatile("s_waitcnt lgkmcnt(0)" ::: "memory");
        __builtin_amdgcn_sched_barrier(0);
        __builtin_amdgcn_s_setprio(1);
        #pragma unroll
        for (int mf = 0; mf < 4; ++mf)
            #pragma unroll
            for (int nf = 0; nf < 2; ++nf) {
                acc[mf][nf + 2] = MFMA16(af[mf][0], b1[nf][0], acc[mf][nf + 2]);
                acc[mf][nf + 2] = MFMA16(af[mf][1], b1[nf][1], acc[mf][nf + 2]);
            }
        __builtin_amdgcn_s_setprio(0);
        __builtin_amdgcn_sched_barrier(0);

        // ---- phase 2 ----
        #pragma unroll
        for (int mf = 0; mf < 4; ++mf) {
            af[mf][0] = *(const bf16x8*)&As[rb][(wr * 128 + 64 + mf * 16 + fr) * 64 + sw0];
            af[mf][1] = *(const bf16x8*)&As[rb][(wr * 128 + 64 + mf * 16 + fr) * 64 + sw1];
        }
        asm volatile("s_waitcnt lgkmcnt(0)" ::: "memory");
        __builtin_amdgcn_sched_barrier(0);
        __builtin_amdgcn_s_setprio(1);
        #pragma unroll
        for (int mf = 0; mf < 4; ++mf)
            #pragma unroll
            for (int nf = 0; nf < 2; ++nf) {
                acc[mf + 4][nf] = MFMA16(af[mf][0], b0[nf][0], acc[mf + 4][nf]);
                acc[mf + 4][nf] = MFMA16(af[mf][1], b0[nf][1], acc[mf + 4][nf]);
            }
        __builtin_amdgcn_s_setprio(0);
        __builtin_amdgcn_sched_barrier(0);

        // ---- phase 3 ----
        __builtin_amdgcn_s_setprio(1);
        #pragma unroll
        for (int mf = 0; mf < 4; ++mf)
            #pragma unroll
            for (int nf = 0; nf < 2; ++nf) {
                acc[mf + 4][nf + 2] = MFMA16(af[mf][0], b1[nf][0], acc[mf + 4][nf + 2]);
                acc[mf + 4][nf + 2] = MFMA16(af[mf][1], b1[nf][1], acc[mf + 4][nf + 2]);
            }
        __builtin_amdgcn_s_setprio(0);
        __builtin_amdgcn_sched_barrier(0);
    }

    // epilogue: row = m0 + wr*128 + mf*16 + fq*4 + e; col = n0 + wc*64 + nf*16 + fr
    #pragma unroll
    for (int mf = 0; mf < 8; ++mf)
        #pragma unroll
        for (int e = 0; e < 4; ++e) {
            int row = m0 + wr * 128 + mf * 16 + fq * 4 + e;
            if (row >= M) continue;
            size_t dstrow = 0;
            if constexpr (EPI == EPI_INIT_TFC) {
                int t2 = row & 7, pp = (row >> 3) % HW_, bb = row / (HW_ * T_);
                dstrow = ((size_t)(bb * T_ + t2) * NTOK + 1 + pp) * DIM;
            }
            #pragma unroll
            for (int nf = 0; nf < 4; ++nf) {
                int col = n0 + wc * 64 + nf * 16 + fr;
                float v = acc[mf][nf][e];
                if constexpr (EPI == EPI_BIAS_ADD) {
                    if (half == 0) v += bias[col];
                    atomicAdd(&xf[(size_t)row * DIM + col], v);
                } else {
                    if constexpr (EPI != EPI_STORE) v += bias[col];
                    if constexpr (EPI == EPI_BIAS_GELU) v = 0.5f * v * (1.0f + erff(v * 0.70710678118654752f));
                    if constexpr (EPI == EPI_STORE || EPI == EPI_BIAS_GELU) {
                        Cg[(size_t)row * N + col] = f2bf(v);
                    } else {  // EPI_INIT_TFC
                        xf[dstrow + col] = xsrc[dstrow + col] + v;
                    }
                }
            }
        }
}

// ---------------------------------------------------------------------------
// LayerNorm fp32 src -> bf16 dst (768 wide, 1 wave/row)
// ---------------------------------------------------------------------------
__global__ __launch_bounds__(256) void ln_f32(
    const float* __restrict__ src, const float* __restrict__ g,
    const float* __restrict__ b, ushort* __restrict__ dst, int rows)
{
    int widx = threadIdx.x >> 6, lane = threadIdx.x & 63;
    int r = blockIdx.x * 4 + widx;
    if (r >= rows) return;
    const float* row = src + (size_t)r * DIM;
    float v[12], sum = 0.f, sq = 0.f;
    #pragma unroll
    for (int c = 0; c < 3; ++c) {
        float4 t = *(const float4*)(row + c * 256 + lane * 4);
        v[c*4+0] = t.x; v[c*4+1] = t.y; v[c*4+2] = t.z; v[c*4+3] = t.w;
        sum += t.x + t.y + t.z + t.w;
        sq  += t.x*t.x + t.y*t.y + t.z*t.z + t.w*t.w;
    }
    sum = wred_sum(sum); sq = wred_sum(sq);
    float mean = sum * (1.f / DIM);
    float var  = sq * (1.f / DIM) - mean * mean;
    float rstd = rsqrtf(var + 1e-5f);
    #pragma unroll
    for (int c = 0; c < 3; ++c) {
        int idx = c * 256 + lane * 4;
        float4 gg = *(const float4*)(g + idx);
        float4 bb = *(const float4*)(b + idx);
        ushort4 o;
        o.x = f2bf((v[c*4+0] - mean) * rstd * gg.x + bb.x);
        o.y = f2bf((v[c*4+1] - mean) * rstd * gg.y + bb.y);
        o.z = f2bf((v[c*4+2] - mean) * rstd * gg.z + bb.z);
        o.w = f2bf((v[c*4+3] - mean) * rstd * gg.w + bb.w);
        *(ushort4*)(dst + (size_t)r * DIM + idx) = o;
    }
}

// ---------------------------------------------------------------------------
// Temporal attention: seq len 8, one wave per (seq, head)
// ---------------------------------------------------------------------------
__global__ __launch_bounds__(256) void attn_temporal(
    const ushort* __restrict__ qkv, ushort* __restrict__ O)
{
    int widx = threadIdx.x >> 6, lane = threadIdx.x & 63;
    int w = blockIdx.x * 4 + widx;
    int s = w / NH, h = w % NH;
    int qi = lane >> 3, kj = lane & 7;

    const ushort* qrow = qkv + (size_t)(s * 8 + qi) * (3 * DIM) + h * HD;
    const ushort* krow = qkv + (size_t)(s * 8 + kj) * (3 * DIM) + DIM + h * HD;
    float d = 0.f;
    #pragma unroll
    for (int c = 0; c < 8; ++c) {
        uint4 qa = *(const uint4*)(qrow + c * 8);
        uint4 ka = *(const uint4*)(krow + c * 8);
        const ushort* qs = (const ushort*)&qa;
        const ushort* ks = (const ushort*)&ka;
        #pragma unroll
        for (int e = 0; e < 8; ++e) d += bf2f(qs[e]) * bf2f(ks[e]);
    }
    float sc = d * 0.125f;
    float mx = sc;
    #pragma unroll
    for (int m = 4; m; m >>= 1) mx = fmaxf(mx, __shfl_xor(mx, m));
    float p = expf(sc - mx);
    float sum = p;
    #pragma unroll
    for (int m = 4; m; m >>= 1) sum += __shfl_xor(sum, m);
    p /= sum;

    float o[8] = {};
    int base = lane & ~7;
    #pragma unroll
    for (int t = 0; t < 8; ++t) {
        float pt = __shfl(p, base + t);
        const ushort* vrow = qkv + (size_t)(s * 8 + t) * (3 * DIM) + 2 * DIM + h * HD + kj * 8;
        uint4 va = *(const uint4*)vrow;
        const ushort* vs = (const ushort*)&va;
        #pragma unroll
        for (int e = 0; e < 8; ++e) o[e] += pt * bf2f(vs[e]);
    }
    ushort out[8];
    #pragma unroll
    for (int e = 0; e < 8; ++e) out[e] = f2bf(o[e]);
    *(uint4*)(O + (size_t)(s * 8 + qi) * DIM + h * HD + kj * 8) = *(const uint4*)out;
}

// ---------------------------------------------------------------------------
// Spatial attention, MFMA. One block per (s,h); 4 waves; 768 blocks.
// ---------------------------------------------------------------------------
#define KS_STRIDE 72
#define VT_STRIDE 208
#define P_STRIDE  208
#define KS_OFF    0
#define VT_OFF    (197 * KS_STRIDE)
#define P_OFF     (VT_OFF + 64 * VT_STRIDE)
#define LDS_TOT   (P_OFF + 4 * 16 * P_STRIDE)

__global__ __launch_bounds__(256, 2) void attn_spatial_mfma(
    const ushort* __restrict__ qkv, ushort* __restrict__ O)
{
    __shared__ ushort lds[LDS_TOT];
    const int tid = threadIdx.x, lane = tid & 63, wid = tid >> 6;
    const int fr = lane & 15, fq = lane >> 4;
    int lin = xcd_lin(blockIdx.x, BT_ * NH);
    const int s = lin / NH, h = lin % NH;
    const size_t base = (size_t)s * NTOK * (3 * DIM);
    const ushort* Qg = qkv + base + h * HD;
    const ushort* Kg = qkv + base + DIM + h * HD;
    const ushort* Vg = qkv + base + 2 * DIM + h * HD;

    for (int chunk = tid; chunk < NTOK * 8; chunk += 256) {
        int r = chunk >> 3, c = (chunk & 7) * 8;
        uint4 v = *(const uint4*)(Kg + (size_t)r * (3 * DIM) + c);
        *(uint4*)&lds[KS_OFF + r * KS_STRIDE + c] = v;
    }
    for (int chunk = tid; chunk < 208 * 8; chunk += 256) {
        int k = chunk >> 3, c = (chunk & 7) * 8;
        uint4 v = {0u, 0u, 0u, 0u};
        if (k < NTOK) v = *(const uint4*)(Vg + (size_t)k * (3 * DIM) + c);
        const ushort* e = (const ushort*)&v;
        #pragma unroll
        for (int j = 0; j < 8; ++j) lds[VT_OFF + (c + j) * VT_STRIDE + k] = e[j];
    }
    __syncthreads();

    ushort* P = &lds[P_OFF + wid * 16 * P_STRIDE];

    for (int qi = wid; qi < 13; qi += 4) {
        int qrow = qi * 16 + fr; if (qrow > NTOK - 1) qrow = NTOK - 1;
        bf16x8 qf0 = *(const bf16x8*)(Qg + (size_t)qrow * (3 * DIM) + fq * 8);
        bf16x8 qf1 = *(const bf16x8*)(Qg + (size_t)qrow * (3 * DIM) + 32 + fq * 8);

        f32x4 sacc[13];
        #pragma unroll
        for (int t = 0; t < 13; ++t) {
            bf16x8 kf0 = *(const bf16x8*)&lds[KS_OFF + (t * 16 + fr) * KS_STRIDE + fq * 8];
            bf16x8 kf1 = *(const bf16x8*)&lds[KS_OFF + (t * 16 + fr) * KS_STRIDE + 32 + fq * 8];
            f32x4 z = {0.f, 0.f, 0.f, 0.f};
            z = MFMA16(kf0, qf0, z);
            sacc[t] = MFMA16(kf1, qf1, z);
        }

        float m = -1e30f;
        #pragma unroll
        for (int t = 0; t < 13; ++t)
            #pragma unroll
            for (int e = 0; e < 4; ++e) {
                int k = t * 16 + fq * 4 + e;
                float v = (k < NTOK) ? sacc[t][e] * 0.125f : -1e30f;
                sacc[t][e] = v;
                m = fmaxf(m, v);
            }
        m = fmaxf(m, __shfl_xor(m, 16));
        m = fmaxf(m, __shfl_xor(m, 32));
        float sum = 0.f;
        #pragma unroll
        for (int t = 0; t < 13; ++t)
            #pragma unroll
            for (int e = 0; e < 4; ++e) {
                float p = expf(sacc[t][e] - m);
                sacc[t][e] = p;
                sum += p;
            }
        sum += __shfl_xor(sum, 16);
        sum += __shfl_xor(sum, 32);
        float rd = 1.f / sum;

        #pragma unroll
        for (int t = 0; t < 13; ++t) {
            ushort2 w0 = { f2bf(sacc[t][0] * rd), f2bf(sacc[t][1] * rd) };
            ushort2 w1 = { f2bf(sacc[t][2] * rd), f2bf(sacc[t][3] * rd) };
            *(ushort2*)&P[fr * P_STRIDE + t * 16 + fq * 4]     = w0;
            *(ushort2*)&P[fr * P_STRIDE + t * 16 + fq * 4 + 2] = w1;
        }

        f32x4 oacc[4] = {};
        #pragma unroll
        for (int st = 0; st < 6; ++st) {
            bf16x8 pf = *(const bf16x8*)&P[fr * P_STRIDE + st * 32 + fq * 8];
            #pragma unroll
            for (int dt = 0; dt < 4; ++dt) {
                bf16x8 vf = *(const bf16x8*)&lds[VT_OFF + (dt * 16 + fr) * VT_STRIDE + st * 32 + fq * 8];
                oacc[dt] = MFMA16(pf, vf, oacc[dt]);
            }
        }
        {
            bf16x8 zz = {};
            bf16x8 pf = zz;
            if (fq < 2) pf = *(const bf16x8*)&P[fr * P_STRIDE + 192 + fq * 8];
            #pragma unroll
            for (int dt = 0; dt < 4; ++dt) {
                bf16x8 vf = zz;
                if (fq < 2) vf = *(const bf16x8*)&lds[VT_OFF + (dt * 16 + fr) * VT_STRIDE + 192 + fq * 8];
                oacc[dt] = MFMA16(pf, vf, oacc[dt]);
            }
        }

        #pragma unroll
        for (int dt = 0; dt < 4; ++dt)
            #pragma unroll
            for (int e = 0; e < 4; ++e) {
                int q = qi * 16 + fq * 4 + e;
                if (q < NTOK)
                    O[(size_t)(s * NTOK + q) * DIM + h * HD + dt * 16 + fr] = f2bf(oacc[dt][e]);
            }
    }
}

// ---------------------------------------------------------------------------
extern "C" void kernel_launch(void* const* d_in, const int* in_sizes, int n_in,
                              void* d_out, int out_size, void* d_ws, size_t ws_size,
                              hipStream_t stream)
{
    const float* x      = (const float*)d_in[0];
    const float* ln1_g  = (const float*)d_in[1];
    const float* ln1_b  = (const float*)d_in[2];
    const float* qkv_w  = (const float*)d_in[3];
    const float* proj_w = (const float*)d_in[4];
    const float* proj_b = (const float*)d_in[5];
    const float* tln_g  = (const float*)d_in[6];
    const float* tln_b  = (const float*)d_in[7];
    const float* tqkv_w = (const float*)d_in[8];
    const float* tproj_w= (const float*)d_in[9];
    const float* tproj_b= (const float*)d_in[10];
    const float* tfc_w  = (const float*)d_in[11];
    const float* tfc_b  = (const float*)d_in[12];
    const float* ln2_g  = (const float*)d_in[13];
    const float* ln2_b  = (const float*)d_in[14];
    const float* fc1_w  = (const float*)d_in[15];
    const float* fc1_b  = (const float*)d_in[16];
    const float* fc2_w  = (const float*)d_in[17];
    const float* fc2_b  = (const float*)d_in[18];

    float* out = (float*)d_out;   // fp32 residual accumulator = final output

    char* p = (char*)d_ws;
    ushort* w_qkv  = (ushort*)p; p += (size_t)(3*DIM*DIM) * 2;
    ushort* w_proj = (ushort*)p; p += (size_t)(DIM*DIM) * 2;
    ushort* w_tqkv = (ushort*)p; p += (size_t)(3*DIM*DIM) * 2;
    ushort* w_tfc  = (ushort*)p; p += (size_t)(DIM*DIM) * 2;
    ushort* tprojT = (ushort*)p; p += (size_t)(DIM*DIM) * 2;
    ushort* w_comb = (ushort*)p; p += (size_t)(DIM*DIM) * 2;
    ushort* w_fc1p = (ushort*)p; p += (size_t)(HIDP*DIM) * 2;
    ushort* w_fc2p = (ushort*)p; p += (size_t)(DIM*HIDP) * 2;
    float*  b_comb = (float*)p;  p += DIM * 4;
    float*  fc1_bp = (float*)p;  p += HIDP * 4;
    ushort* bufA   = (ushort*)p; p += (size_t)MROWS * DIM * 2;
    ushort* bufC   = (ushort*)p; p += (size_t)MROWS * DIM * 2;
    ushort* bufB   = (ushort*)p;  // MROWS*3*DIM bf16 (also holds [MROWS][1280])

    prep<<<dim3(PREP_GRID), dim3(256), 0, stream>>>(
        x, tln_g, tln_b, qkv_w, proj_w, tqkv_w, tproj_w, tproj_b,
        tfc_w, tfc_b, fc1_w, fc1_b, fc2_w,
        w_qkv, w_proj, w_tqkv, w_tfc, tprojT, w_fc1p, w_fc2p,
        fc1_bp, b_comb, bufA, out);

    // SPLITK: grid = nm*nn*halves; koff = per-half K offset (elems)
    #define GEMM256(KV, LDV, EPI, A, W, BIAS, C, XS, XF, M, N, GRP, SPLITK, KOFF) \
        gemm256<KV, LDV, EPI><<<dim3((((M) + 255) / 256) * ((N) / 256) * (SPLITK)), dim3(512), 0, stream>>>( \
            A, W, BIAS, C, XS, XF, M, N, ((M) + 255) / 256, (N) / 256, GRP, KOFF, \
            nullptr, nullptr, nullptr, 0, 0, 0, 0, 0x7fffffff)

    // ---- temporal branch: tqkv GEMM with W_comb folded in (dual problem)
    {
        int nm = (TROWS + 255) / 256, nn = (3 * DIM) / 256;   // 49 x 9 = 441
        int split = nm * nn;
        gemm256<DIM, DIM, EPI_STORE><<<dim3(split + 9), dim3(512), 0, stream>>>(
            bufA, w_tqkv, nullptr, bufB, nullptr, nullptr, TROWS, 3 * DIM, nm, nn, 1, 0,
            w_tfc, tprojT, w_comb, DIM, DIM, 3, 3, split);
    }
    attn_temporal<<<dim3(TROWS * NH / 8 / 4), dim3(256), 0, stream>>>(bufB, bufC);
    GEMM256(DIM, DIM, EPI_INIT_TFC, bufC, w_comb, b_comb, nullptr, x, out, TROWS, DIM, 1, 1, 0);

    // ---- spatial attention ----
    ln_f32<<<dim3((MROWS + 3) / 4), dim3(256), 0, stream>>>(out, ln1_g, ln1_b, bufA, MROWS);
    GEMM256(DIM, DIM, EPI_STORE, bufA, w_qkv, nullptr, bufB, nullptr, nullptr, MROWS, 3 * DIM, 1, 1, 0);
    attn_spatial_mfma<<<dim3(BT_ * NH), dim3(256), 0, stream>>>(bufB, bufC);
    // proj: split-K=2 (K=768 -> 2x384), atomicAdd into residual
    GEMM256(384, DIM, EPI_BIAS_ADD, bufC, w_proj, proj_b, nullptr, nullptr, out, MROWS, DIM, 1, 2, 384);

    // ---- MLP (fc1 N padded to 1280; fc2 split-K=2 over native K=1152) ----
    ln_f32<<<dim3((MROWS + 3) / 4), dim3(256), 0, stream>>>(out, ln2_g, ln2_b, bufA, MROWS);
    GEMM256(DIM, DIM, EPI_BIAS_GELU, bufA, w_fc1p, fc1_bp, bufB, nullptr, nullptr, MROWS, HIDP, 1, 1, 0);
    GEMM256(576, HIDP, EPI_BIAS_ADD, bufB, w_fc2p, fc2_b, nullptr, nullptr, out, MROWS, DIM, 1, 2, 576);
    #undef GEMM256
}

// Round 14
// 376.044 us; speedup vs baseline: 1.2374x; 1.2374x over previous
//
#include <hip/hip_runtime.h>
#include <hip/hip_bf16.h>

// ---------------------------------------------------------------------------
// FactorizedAttentionBlock (TimeSformer divided space-time attention)
// DIM=768, NH=12, HD=64, HID=1152(pad 1280), B=8, T=8, HW=196, N=197, BT=64
// FP32 in/out. bf16 MFMA GEMMs + MFMA flash attention. fp32 residual in d_out.
// R14: revert to R11 exactly (best measured: 376.1us). R12 de-barrier (+20us),
//      R13 split-K atomics (+89us) both regressed; R7/R11 4-phase schedule is
//      the empirical minimum for this 256^2 @ K<=1152 shape.
// ---------------------------------------------------------------------------

#define DIM   768
#define NH    12
#define HD    64
#define HID   1152
#define HIDP  1280
#define B_    8
#define T_    8
#define HW_   196
#define NTOK  197
#define BT_   64
#define MROWS (BT_ * NTOK)        // 12608
#define TROWS (B_ * HW_ * T_)     // 12544

typedef __bf16 bf16x8 __attribute__((ext_vector_type(8)));
typedef float  f32x4  __attribute__((ext_vector_type(4)));

__device__ inline float bf2f(ushort u) { return __uint_as_float(((unsigned)u) << 16); }
__device__ inline ushort f2bf(float f) {
    unsigned u = __float_as_uint(f);
    unsigned r = (u + 0x7fffu + ((u >> 16) & 1u)) >> 16;
    return (ushort)r;
}

__device__ inline float wred_sum(float v) {
    #pragma unroll
    for (int m = 32; m; m >>= 1) v += __shfl_xor(v, m);
    return v;
}

__device__ __forceinline__ void gload_lds16(const void* g, void* l) {
    __builtin_amdgcn_global_load_lds(
        (const __attribute__((address_space(1))) unsigned int*)g,
        (__attribute__((address_space(3))) unsigned int*)l, 16, 0, 0);
}

// XCD-bijective remap (m204)
__device__ __forceinline__ int xcd_lin(int gid, int nwg) {
    int q = nwg >> 3, r = nwg & 7;
    int xcd = gid & 7, idx = gid >> 3;
    return (xcd < r ? xcd * (q + 1) : r * (q + 1) + (xcd - r) * q) + idx;
}

#define MFMA16(a, b, c) __builtin_amdgcn_mfma_f32_16x16x32_bf16(a, b, c, 0, 0, 0)

// ---------------------------------------------------------------------------
// prep: single fused prep kernel, block-range dispatch.
//   [0,576)            : tproj transpose+cast -> tprojT
//   [576,768)          : b_comb = tfc_w @ tproj_b + tfc_b
//   [768,768+3136)     : ln_gather(x) -> bufA  (temporal LN)
//   rest               : flat segments — weight casts, fc1/fc2 pads,
//                        fc1 bias pad, init_cls rows of out
// ---------------------------------------------------------------------------
#define PREP_T0 576
#define PREP_T1 (PREP_T0 + 192)
#define PREP_T2 (PREP_T1 + TROWS / 4)
#define FL_DD8  73728
#define FL_C0   (3 * FL_DD8)              // qkv
#define FL_C1   (FL_C0 + FL_DD8)          // proj
#define FL_C2   (FL_C1 + 3 * FL_DD8)      // tqkv
#define FL_C3   (FL_C2 + FL_DD8)          // tfc
#define FL_C4   (FL_C3 + HID * DIM / 8)   // fc1 rows
#define FL_C5   (FL_C4 + (HIDP - HID) * DIM / 8)  // fc1 pad rows
#define FL_C6   (FL_C5 + DIM * HIDP / 8)  // fc2 padded
#define FL_C7   (FL_C6 + HIDP / 8)        // fc1 bias pad
#define FL_C8   (FL_C7 + BT_ * DIM / 8)   // init_cls
#define PREP_GRID (PREP_T2 + (FL_C8 + 255) / 256)

__global__ __launch_bounds__(256) void prep(
    const float* __restrict__ x, const float* __restrict__ tln_g, const float* __restrict__ tln_b,
    const float* __restrict__ qkv_w, const float* __restrict__ proj_w,
    const float* __restrict__ tqkv_w, const float* __restrict__ tproj_w,
    const float* __restrict__ tproj_b, const float* __restrict__ tfc_wf,
    const float* __restrict__ tfc_b, const float* __restrict__ fc1_w,
    const float* __restrict__ fc1_b, const float* __restrict__ fc2_w,
    ushort* __restrict__ w_qkv, ushort* __restrict__ w_proj,
    ushort* __restrict__ w_tqkv, ushort* __restrict__ w_tfc,
    ushort* __restrict__ tprojT, ushort* __restrict__ w_fc1p,
    ushort* __restrict__ w_fc2p, float* __restrict__ fc1_bp,
    float* __restrict__ b_comb, ushort* __restrict__ bufA, float* __restrict__ out)
{
    __shared__ float tsm[32][33];
    int b = blockIdx.x, tid = threadIdx.x;

    if (b < PREP_T0) {             // ---- tproj transpose+cast
        int bx = b % 24, by = b / 24;
        int lx = tid & 31, ly = tid >> 5;
        #pragma unroll
        for (int i = 0; i < 32; i += 8)
            tsm[ly + i][lx] = tproj_w[(size_t)(by * 32 + ly + i) * DIM + bx * 32 + lx];
        __syncthreads();
        #pragma unroll
        for (int i = 0; i < 32; i += 8)
            tprojT[(size_t)(bx * 32 + ly + i) * DIM + by * 32 + lx] = f2bf(tsm[lx][ly + i]);
        return;
    }
    if (b < PREP_T1) {             // ---- b_comb
        int w = (b - PREP_T0) * 4 + (tid >> 6), lane = tid & 63;
        float s = 0.f;
        for (int j = lane; j < DIM; j += 64) s += tfc_wf[(size_t)w * DIM + j] * tproj_b[j];
        s = wred_sum(s);
        if (lane == 0) b_comb[w] = s + tfc_b[w];
        return;
    }
    if (b < PREP_T2) {             // ---- ln_gather -> bufA
        int widx = tid >> 6, lane = tid & 63;
        int r = (b - PREP_T1) * 4 + widx;
        int t = r & 7, pp = (r >> 3) % HW_, bb = r / (HW_ * T_);
        const float* row = x + ((size_t)(bb * T_ + t) * NTOK + 1 + pp) * DIM;
        float v[12], sum = 0.f, sq = 0.f;
        #pragma unroll
        for (int c = 0; c < 3; ++c) {
            float4 t4 = *(const float4*)(row + c * 256 + lane * 4);
            v[c*4+0] = t4.x; v[c*4+1] = t4.y; v[c*4+2] = t4.z; v[c*4+3] = t4.w;
            sum += t4.x + t4.y + t4.z + t4.w;
            sq  += t4.x*t4.x + t4.y*t4.y + t4.z*t4.z + t4.w*t4.w;
        }
        sum = wred_sum(sum); sq = wred_sum(sq);
        float mean = sum * (1.f / DIM);
        float var  = sq * (1.f / DIM) - mean * mean;
        float rstd = rsqrtf(var + 1e-5f);
        #pragma unroll
        for (int c = 0; c < 3; ++c) {
            int idx = c * 256 + lane * 4;
            float4 gg = *(const float4*)(tln_g + idx);
            float4 bb2 = *(const float4*)(tln_b + idx);
            ushort4 o;
            o.x = f2bf((v[c*4+0] - mean) * rstd * gg.x + bb2.x);
            o.y = f2bf((v[c*4+1] - mean) * rstd * gg.y + bb2.y);
            o.z = f2bf((v[c*4+2] - mean) * rstd * gg.z + bb2.z);
            o.w = f2bf((v[c*4+3] - mean) * rstd * gg.w + bb2.w);
            *(ushort4*)(bufA + (size_t)r * DIM + idx) = o;
        }
        return;
    }

    int i = (b - PREP_T2) * 256 + tid;
    if (i >= FL_C8) return;
    if (i < FL_C4) {
        const float* s; ushort* d; int base;
        if      (i < FL_C0) { s = qkv_w;  d = w_qkv;  base = 0;     }
        else if (i < FL_C1) { s = proj_w; d = w_proj; base = FL_C0; }
        else if (i < FL_C2) { s = tqkv_w; d = w_tqkv; base = FL_C1; }
        else if (i < FL_C3) { s = tfc_wf; d = w_tfc;  base = FL_C2; }
        else                { s = fc1_w;  d = w_fc1p; base = FL_C3; }
        int k = i - base;
        float4 a = *(const float4*)(s + (size_t)k * 8);
        float4 bb = *(const float4*)(s + (size_t)k * 8 + 4);
        ushort o[8] = {f2bf(a.x), f2bf(a.y), f2bf(a.z), f2bf(a.w),
                       f2bf(bb.x), f2bf(bb.y), f2bf(bb.z), f2bf(bb.w)};
        *(uint4*)(d + (size_t)k * 8) = *(const uint4*)o;
    } else if (i < FL_C5) {
        int k = i - FL_C4;
        uint4 z = {0u, 0u, 0u, 0u};
        *(uint4*)(w_fc1p + (size_t)HID * DIM + (size_t)k * 8) = z;
    } else if (i < FL_C6) {
        int k = i - FL_C5;
        int r = k / (HIDP / 8), c8 = (k % (HIDP / 8)) * 8;
        ushort o[8];
        if (c8 < HID) {
            const float* s = fc2_w + (size_t)r * HID + c8;
            #pragma unroll
            for (int e = 0; e < 8; ++e) o[e] = f2bf(s[e]);
        } else {
            #pragma unroll
            for (int e = 0; e < 8; ++e) o[e] = 0;
        }
        *(uint4*)(w_fc2p + (size_t)r * HIDP + c8) = *(const uint4*)o;
    } else if (i < FL_C7) {
        int k = (i - FL_C6) * 8;
        #pragma unroll
        for (int e = 0; e < 8; ++e) fc1_bp[k + e] = (k + e < HID) ? fc1_b[k + e] : 0.f;
    } else {
        int k = (i - FL_C7) * 8;
        int r = k / DIM, c = k % DIM;
        size_t off = (size_t)r * NTOK * DIM + c;
        *(float4*)(out + off)     = *(const float4*)(x + off);
        *(float4*)(out + off + 4) = *(const float4*)(x + off + 4);
    }
}

// ---------------------------------------------------------------------------
// gemm256 (R7/R11 schedule — empirical best): C[M,N] = A[M,K] @ W[N,K]^T.
// 256x256 tile, 8 waves (2Mx4N), per-wave 128x64. BK=64, dbuf LDS (128KB),
// 4 phases/K-tile, one vmcnt(0)+barrier per K-tile, setprio on MFMA,
// XOR-swizzled LDS via pre-swizzled source. Dual-problem support: blocks
// >= split run problem 2 (used to fold W_comb into the tqkv dispatch).
// ---------------------------------------------------------------------------
enum { EPI_STORE = 0, EPI_BIAS_GELU = 1, EPI_BIAS_ADD = 2, EPI_INIT_TFC = 3 };

template <int KK, int EPI>
__global__ __launch_bounds__(512, 1) void gemm256(
    const ushort* __restrict__ Ag, const ushort* __restrict__ Wg,
    const float* __restrict__ bias, ushort* __restrict__ Cg,
    const float* __restrict__ xsrc, float* __restrict__ xf,
    int M, int N, int nm, int nn, int grp,
    const ushort* A2, const ushort* W2, ushort* C2,
    int M2, int N2, int nm2, int nn2, int split)
{
    __shared__ ushort As[2][256 * 64];
    __shared__ ushort Bs[2][256 * 64];

    const int tid  = threadIdx.x;
    const int lane = tid & 63, wid = tid >> 6;
    const int wr = wid >> 2, wc = wid & 3;
    const int fr = lane & 15, fq = lane >> 4;

    int bid = blockIdx.x;
    if (bid >= split) {            // problem 2 (W_comb)
        Ag = A2; Wg = W2; Cg = C2; M = M2; N = N2; nm = nm2; nn = nn2;
        bid -= split;
    }

    int lin = xcd_lin(bid, nm * nn);
    int per = grp * nn;
    int g2 = lin / per, rem = lin % per;
    int bm = g2 * grp;
    int gm = nm - bm; if (gm > grp) gm = grp;
    const int m0 = (bm + rem % gm) * 256;
    const int n0 = (rem / gm) * 256;

    const int srow = wid * 8 + (lane >> 3);
    const int scol = 8 * ((lane & 7) ^ (lane >> 3));
    const ushort* aP[4]; const ushort* bP[4];
    #pragma unroll
    for (int j = 0; j < 4; ++j) {
        int ra = m0 + j * 64 + srow; if (ra >= M) ra = M - 1;
        aP[j] = Ag + (size_t)ra * KK + scol;
        bP[j] = Wg + (size_t)(n0 + j * 64 + srow) * KK + scol;
    }
    const int ldso = (wid * 8) * 64;

    f32x4 acc[8][4] = {};
    bf16x8 af[4][2], b0[2][2], b1[2][2];

    const int sw0 = (fq * 8) ^ ((fr & 7) * 8);
    const int sw1 = (32 + fq * 8) ^ ((fr & 7) * 8);

    #pragma unroll
    for (int j = 0; j < 4; ++j) gload_lds16(aP[j], &As[0][j * 4096 + ldso]);
    #pragma unroll
    for (int j = 0; j < 4; ++j) gload_lds16(bP[j], &Bs[0][j * 4096 + ldso]);

    constexpr int NT = KK / 64;
    #pragma unroll
    for (int t = 0; t < NT; ++t) {
        const int rb = t & 1, wb = rb ^ 1;
        const bool st = (t + 1 < NT);
        const int kw = (t + 1) * 64;

        asm volatile("s_waitcnt vmcnt(0)" ::: "memory");
        __builtin_amdgcn_s_barrier();
        __builtin_amdgcn_sched_barrier(0);

        // ---- phase 0 ----
        #pragma unroll
        for (int mf = 0; mf < 4; ++mf) {
            af[mf][0] = *(const bf16x8*)&As[rb][(wr * 128 + mf * 16 + fr) * 64 + sw0];
            af[mf][1] = *(const bf16x8*)&As[rb][(wr * 128 + mf * 16 + fr) * 64 + sw1];
        }
        #pragma unroll
        for (int nf = 0; nf < 2; ++nf) {
            b0[nf][0] = *(const bf16x8*)&Bs[rb][(wc * 64 + nf * 16 + fr) * 64 + sw0];
            b0[nf][1] = *(const bf16x8*)&Bs[rb][(wc * 64 + nf * 16 + fr) * 64 + sw1];
        }
        if (st) {
            #pragma unroll
            for (int j = 0; j < 4; ++j) gload_lds16(aP[j] + kw, &As[wb][j * 4096 + ldso]);
        }
        asm volatile("s_waitcnt lgkmcnt(0)" ::: "memory");
        __builtin_amdgcn_sched_barrier(0);
        __builtin_amdgcn_s_setprio(1);
        #pragma unroll
        for (int mf = 0; mf < 4; ++mf)
            #pragma unroll
            for (int nf = 0; nf < 2; ++nf) {
                acc[mf][nf] = MFMA16(af[mf][0], b0[nf][0], acc[mf][nf]);
                acc[mf][nf] = MFMA16(af[mf][1], b0[nf][1], acc[mf][nf]);
            }
        __builtin_amdgcn_s_setprio(0);
        __builtin_amdgcn_sched_barrier(0);

        // ---- phase 1 ----
        #pragma unroll
        for (int nf = 0; nf < 2; ++nf) {
            b1[nf][0] = *(const bf16x8*)&Bs[rb][(wc * 64 + (nf + 2) * 16 + fr) * 64 + sw0];
            b1[nf][1] = *(const bf16x8*)&Bs[rb][(wc * 64 + (nf + 2) * 16 + fr) * 64 + sw1];
        }
        if (st) {
            #pragma unroll
            for (int j = 0; j < 4; ++j) gload_lds16(bP[j] + kw, &Bs[wb][j * 4096 + ldso]);
        }
        asm volatile("s_waitcnt lgkmcnt(0)" ::: "memory");
        __builtin_amdgcn_sched_barrier(0);
        __builtin_amdgcn_s_setprio(1);
        #pragma unroll
        for (int mf = 0; mf < 4; ++mf)
            #pragma unroll
            for (int nf = 0; nf < 2; ++nf) {
                acc[mf][nf + 2] = MFMA16(af[mf][0], b1[nf][0], acc[mf][nf + 2]);
                acc[mf][nf + 2] = MFMA16(af[mf][1], b1[nf][1], acc[mf][nf + 2]);
            }
        __builtin_amdgcn_s_setprio(0);
        __builtin_amdgcn_sched_barrier(0);

        // ---- phase 2 ----
        #pragma unroll
        for (int mf = 0; mf < 4; ++mf) {
            af[mf][0] = *(const bf16x8*)&As[rb][(wr * 128 + 64 + mf * 16 + fr) * 64 + sw0];
            af[mf][1] = *(const bf16x8*)&As[rb][(wr * 128 + 64 + mf * 16 + fr) * 64 + sw1];
        }
        asm volatile("s_waitcnt lgkmcnt(0)" ::: "memory");
        __builtin_amdgcn_sched_barrier(0);
        __builtin_amdgcn_s_setprio(1);
        #pragma unroll
        for (int mf = 0; mf < 4; ++mf)
            #pragma unroll
            for (int nf = 0; nf < 2; ++nf) {
                acc[mf + 4][nf] = MFMA16(af[mf][0], b0[nf][0], acc[mf + 4][nf]);
                acc[mf + 4][nf] = MFMA16(af[mf][1], b0[nf][1], acc[mf + 4][nf]);
            }
        __builtin_amdgcn_s_setprio(0);
        __builtin_amdgcn_sched_barrier(0);

        // ---- phase 3 ----
        __builtin_amdgcn_s_setprio(1);
        #pragma unroll
        for (int mf = 0; mf < 4; ++mf)
            #pragma unroll
            for (int nf = 0; nf < 2; ++nf) {
                acc[mf + 4][nf + 2] = MFMA16(af[mf][0], b1[nf][0], acc[mf + 4][nf + 2]);
                acc[mf + 4][nf + 2] = MFMA16(af[mf][1], b1[nf][1], acc[mf + 4][nf + 2]);
            }
        __builtin_amdgcn_s_setprio(0);
        __builtin_amdgcn_sched_barrier(0);
    }

    // epilogue: row = m0 + wr*128 + mf*16 + fq*4 + e; col = n0 + wc*64 + nf*16 + fr
    #pragma unroll
    for (int mf = 0; mf < 8; ++mf)
        #pragma unroll
        for (int e = 0; e < 4; ++e) {
            int row = m0 + wr * 128 + mf * 16 + fq * 4 + e;
            if (row >= M) continue;
            size_t dstrow = 0;
            if constexpr (EPI == EPI_INIT_TFC) {
                int t2 = row & 7, pp = (row >> 3) % HW_, bb = row / (HW_ * T_);
                dstrow = ((size_t)(bb * T_ + t2) * NTOK + 1 + pp) * DIM;
            }
            #pragma unroll
            for (int nf = 0; nf < 4; ++nf) {
                int col = n0 + wc * 64 + nf * 16 + fr;
                float v = acc[mf][nf][e];
                if constexpr (EPI != EPI_STORE) v += bias[col];
                if constexpr (EPI == EPI_BIAS_GELU) v = 0.5f * v * (1.0f + erff(v * 0.70710678118654752f));
                if constexpr (EPI == EPI_STORE || EPI == EPI_BIAS_GELU) {
                    Cg[(size_t)row * N + col] = f2bf(v);
                } else if constexpr (EPI == EPI_BIAS_ADD) {
                    xf[(size_t)row * DIM + col] += v;
                } else {
                    xf[dstrow + col] = xsrc[dstrow + col] + v;
                }
            }
        }
}

// ---------------------------------------------------------------------------
// LayerNorm fp32 src -> bf16 dst (768 wide, 1 wave/row)
// ---------------------------------------------------------------------------
__global__ __launch_bounds__(256) void ln_f32(
    const float* __restrict__ src, const float* __restrict__ g,
    const float* __restrict__ b, ushort* __restrict__ dst, int rows)
{
    int widx = threadIdx.x >> 6, lane = threadIdx.x & 63;
    int r = blockIdx.x * 4 + widx;
    if (r >= rows) return;
    const float* row = src + (size_t)r * DIM;
    float v[12], sum = 0.f, sq = 0.f;
    #pragma unroll
    for (int c = 0; c < 3; ++c) {
        float4 t = *(const float4*)(row + c * 256 + lane * 4);
        v[c*4+0] = t.x; v[c*4+1] = t.y; v[c*4+2] = t.z; v[c*4+3] = t.w;
        sum += t.x + t.y + t.z + t.w;
        sq  += t.x*t.x + t.y*t.y + t.z*t.z + t.w*t.w;
    }
    sum = wred_sum(sum); sq = wred_sum(sq);
    float mean = sum * (1.f / DIM);
    float var  = sq * (1.f / DIM) - mean * mean;
    float rstd = rsqrtf(var + 1e-5f);
    #pragma unroll
    for (int c = 0; c < 3; ++c) {
        int idx = c * 256 + lane * 4;
        float4 gg = *(const float4*)(g + idx);
        float4 bb = *(const float4*)(b + idx);
        ushort4 o;
        o.x = f2bf((v[c*4+0] - mean) * rstd * gg.x + bb.x);
        o.y = f2bf((v[c*4+1] - mean) * rstd * gg.y + bb.y);
        o.z = f2bf((v[c*4+2] - mean) * rstd * gg.z + bb.z);
        o.w = f2bf((v[c*4+3] - mean) * rstd * gg.w + bb.w);
        *(ushort4*)(dst + (size_t)r * DIM + idx) = o;
    }
}

// ---------------------------------------------------------------------------
// Temporal attention: seq len 8, one wave per (seq, head)
// ---------------------------------------------------------------------------
__global__ __launch_bounds__(256) void attn_temporal(
    const ushort* __restrict__ qkv, ushort* __restrict__ O)
{
    int widx = threadIdx.x >> 6, lane = threadIdx.x & 63;
    int w = blockIdx.x * 4 + widx;
    int s = w / NH, h = w % NH;
    int qi = lane >> 3, kj = lane & 7;

    const ushort* qrow = qkv + (size_t)(s * 8 + qi) * (3 * DIM) + h * HD;
    const ushort* krow = qkv + (size_t)(s * 8 + kj) * (3 * DIM) + DIM + h * HD;
    float d = 0.f;
    #pragma unroll
    for (int c = 0; c < 8; ++c) {
        uint4 qa = *(const uint4*)(qrow + c * 8);
        uint4 ka = *(const uint4*)(krow + c * 8);
        const ushort* qs = (const ushort*)&qa;
        const ushort* ks = (const ushort*)&ka;
        #pragma unroll
        for (int e = 0; e < 8; ++e) d += bf2f(qs[e]) * bf2f(ks[e]);
    }
    float sc = d * 0.125f;
    float mx = sc;
    #pragma unroll
    for (int m = 4; m; m >>= 1) mx = fmaxf(mx, __shfl_xor(mx, m));
    float p = expf(sc - mx);
    float sum = p;
    #pragma unroll
    for (int m = 4; m; m >>= 1) sum += __shfl_xor(sum, m);
    p /= sum;

    float o[8] = {};
    int base = lane & ~7;
    #pragma unroll
    for (int t = 0; t < 8; ++t) {
        float pt = __shfl(p, base + t);
        const ushort* vrow = qkv + (size_t)(s * 8 + t) * (3 * DIM) + 2 * DIM + h * HD + kj * 8;
        uint4 va = *(const uint4*)vrow;
        const ushort* vs = (const ushort*)&va;
        #pragma unroll
        for (int e = 0; e < 8; ++e) o[e] += pt * bf2f(vs[e]);
    }
    ushort out[8];
    #pragma unroll
    for (int e = 0; e < 8; ++e) out[e] = f2bf(o[e]);
    *(uint4*)(O + (size_t)(s * 8 + qi) * DIM + h * HD + kj * 8) = *(const uint4*)out;
}

// ---------------------------------------------------------------------------
// Spatial attention, MFMA. One block per (s,h); 4 waves; 768 blocks.
// ---------------------------------------------------------------------------
#define KS_STRIDE 72
#define VT_STRIDE 208
#define P_STRIDE  208
#define KS_OFF    0
#define VT_OFF    (197 * KS_STRIDE)
#define P_OFF     (VT_OFF + 64 * VT_STRIDE)
#define LDS_TOT   (P_OFF + 4 * 16 * P_STRIDE)

__global__ __launch_bounds__(256, 2) void attn_spatial_mfma(
    const ushort* __restrict__ qkv, ushort* __restrict__ O)
{
    __shared__ ushort lds[LDS_TOT];
    const int tid = threadIdx.x, lane = tid & 63, wid = tid >> 6;
    const int fr = lane & 15, fq = lane >> 4;
    int lin = xcd_lin(blockIdx.x, BT_ * NH);
    const int s = lin / NH, h = lin % NH;
    const size_t base = (size_t)s * NTOK * (3 * DIM);
    const ushort* Qg = qkv + base + h * HD;
    const ushort* Kg = qkv + base + DIM + h * HD;
    const ushort* Vg = qkv + base + 2 * DIM + h * HD;

    for (int chunk = tid; chunk < NTOK * 8; chunk += 256) {
        int r = chunk >> 3, c = (chunk & 7) * 8;
        uint4 v = *(const uint4*)(Kg + (size_t)r * (3 * DIM) + c);
        *(uint4*)&lds[KS_OFF + r * KS_STRIDE + c] = v;
    }
    for (int chunk = tid; chunk < 208 * 8; chunk += 256) {
        int k = chunk >> 3, c = (chunk & 7) * 8;
        uint4 v = {0u, 0u, 0u, 0u};
        if (k < NTOK) v = *(const uint4*)(Vg + (size_t)k * (3 * DIM) + c);
        const ushort* e = (const ushort*)&v;
        #pragma unroll
        for (int j = 0; j < 8; ++j) lds[VT_OFF + (c + j) * VT_STRIDE + k] = e[j];
    }
    __syncthreads();

    ushort* P = &lds[P_OFF + wid * 16 * P_STRIDE];

    for (int qi = wid; qi < 13; qi += 4) {
        int qrow = qi * 16 + fr; if (qrow > NTOK - 1) qrow = NTOK - 1;
        bf16x8 qf0 = *(const bf16x8*)(Qg + (size_t)qrow * (3 * DIM) + fq * 8);
        bf16x8 qf1 = *(const bf16x8*)(Qg + (size_t)qrow * (3 * DIM) + 32 + fq * 8);

        f32x4 sacc[13];
        #pragma unroll
        for (int t = 0; t < 13; ++t) {
            bf16x8 kf0 = *(const bf16x8*)&lds[KS_OFF + (t * 16 + fr) * KS_STRIDE + fq * 8];
            bf16x8 kf1 = *(const bf16x8*)&lds[KS_OFF + (t * 16 + fr) * KS_STRIDE + 32 + fq * 8];
            f32x4 z = {0.f, 0.f, 0.f, 0.f};
            z = MFMA16(kf0, qf0, z);
            sacc[t] = MFMA16(kf1, qf1, z);
        }

        float m = -1e30f;
        #pragma unroll
        for (int t = 0; t < 13; ++t)
            #pragma unroll
            for (int e = 0; e < 4; ++e) {
                int k = t * 16 + fq * 4 + e;
                float v = (k < NTOK) ? sacc[t][e] * 0.125f : -1e30f;
                sacc[t][e] = v;
                m = fmaxf(m, v);
            }
        m = fmaxf(m, __shfl_xor(m, 16));
        m = fmaxf(m, __shfl_xor(m, 32));
        float sum = 0.f;
        #pragma unroll
        for (int t = 0; t < 13; ++t)
            #pragma unroll
            for (int e = 0; e < 4; ++e) {
                float p = expf(sacc[t][e] - m);
                sacc[t][e] = p;
                sum += p;
            }
        sum += __shfl_xor(sum, 16);
        sum += __shfl_xor(sum, 32);
        float rd = 1.f / sum;

        #pragma unroll
        for (int t = 0; t < 13; ++t) {
            ushort2 w0 = { f2bf(sacc[t][0] * rd), f2bf(sacc[t][1] * rd) };
            ushort2 w1 = { f2bf(sacc[t][2] * rd), f2bf(sacc[t][3] * rd) };
            *(ushort2*)&P[fr * P_STRIDE + t * 16 + fq * 4]     = w0;
            *(ushort2*)&P[fr * P_STRIDE + t * 16 + fq * 4 + 2] = w1;
        }

        f32x4 oacc[4] = {};
        #pragma unroll
        for (int st = 0; st < 6; ++st) {
            bf16x8 pf = *(const bf16x8*)&P[fr * P_STRIDE + st * 32 + fq * 8];
            #pragma unroll
            for (int dt = 0; dt < 4; ++dt) {
                bf16x8 vf = *(const bf16x8*)&lds[VT_OFF + (dt * 16 + fr) * VT_STRIDE + st * 32 + fq * 8];
                oacc[dt] = MFMA16(pf, vf, oacc[dt]);
            }
        }
        {
            bf16x8 zz = {};
            bf16x8 pf = zz;
            if (fq < 2) pf = *(const bf16x8*)&P[fr * P_STRIDE + 192 + fq * 8];
            #pragma unroll
            for (int dt = 0; dt < 4; ++dt) {
                bf16x8 vf = zz;
                if (fq < 2) vf = *(const bf16x8*)&lds[VT_OFF + (dt * 16 + fr) * VT_STRIDE + 192 + fq * 8];
                oacc[dt] = MFMA16(pf, vf, oacc[dt]);
            }
        }

        #pragma unroll
        for (int dt = 0; dt < 4; ++dt)
            #pragma unroll
            for (int e = 0; e < 4; ++e) {
                int q = qi * 16 + fq * 4 + e;
                if (q < NTOK)
                    O[(size_t)(s * NTOK + q) * DIM + h * HD + dt * 16 + fr] = f2bf(oacc[dt][e]);
            }
    }
}

// ---------------------------------------------------------------------------
extern "C" void kernel_launch(void* const* d_in, const int* in_sizes, int n_in,
                              void* d_out, int out_size, void* d_ws, size_t ws_size,
                              hipStream_t stream)
{
    const float* x      = (const float*)d_in[0];
    const float* ln1_g  = (const float*)d_in[1];
    const float* ln1_b  = (const float*)d_in[2];
    const float* qkv_w  = (const float*)d_in[3];
    const float* proj_w = (const float*)d_in[4];
    const float* proj_b = (const float*)d_in[5];
    const float* tln_g  = (const float*)d_in[6];
    const float* tln_b  = (const float*)d_in[7];
    const float* tqkv_w = (const float*)d_in[8];
    const float* tproj_w= (const float*)d_in[9];
    const float* tproj_b= (const float*)d_in[10];
    const float* tfc_w  = (const float*)d_in[11];
    const float* tfc_b  = (const float*)d_in[12];
    const float* ln2_g  = (const float*)d_in[13];
    const float* ln2_b  = (const float*)d_in[14];
    const float* fc1_w  = (const float*)d_in[15];
    const float* fc1_b  = (const float*)d_in[16];
    const float* fc2_w  = (const float*)d_in[17];
    const float* fc2_b  = (const float*)d_in[18];

    float* out = (float*)d_out;   // fp32 residual accumulator = final output

    char* p = (char*)d_ws;
    ushort* w_qkv  = (ushort*)p; p += (size_t)(3*DIM*DIM) * 2;
    ushort* w_proj = (ushort*)p; p += (size_t)(DIM*DIM) * 2;
    ushort* w_tqkv = (ushort*)p; p += (size_t)(3*DIM*DIM) * 2;
    ushort* w_tfc  = (ushort*)p; p += (size_t)(DIM*DIM) * 2;
    ushort* tprojT = (ushort*)p; p += (size_t)(DIM*DIM) * 2;
    ushort* w_comb = (ushort*)p; p += (size_t)(DIM*DIM) * 2;
    ushort* w_fc1p = (ushort*)p; p += (size_t)(HIDP*DIM) * 2;
    ushort* w_fc2p = (ushort*)p; p += (size_t)(DIM*HIDP) * 2;
    float*  b_comb = (float*)p;  p += DIM * 4;
    float*  fc1_bp = (float*)p;  p += HIDP * 4;
    ushort* bufA   = (ushort*)p; p += (size_t)MROWS * DIM * 2;
    ushort* bufC   = (ushort*)p; p += (size_t)MROWS * DIM * 2;
    ushort* bufB   = (ushort*)p;  // MROWS*3*DIM bf16 (also holds [MROWS][1280])

    // ---- fused prep: transposes, casts, pads, b_comb, ln_gather, init_cls
    prep<<<dim3(PREP_GRID), dim3(256), 0, stream>>>(
        x, tln_g, tln_b, qkv_w, proj_w, tqkv_w, tproj_w, tproj_b,
        tfc_w, tfc_b, fc1_w, fc1_b, fc2_w,
        w_qkv, w_proj, w_tqkv, w_tfc, tprojT, w_fc1p, w_fc2p,
        fc1_bp, b_comb, bufA, out);

    #define GEMM256(KV, EPI, A, W, BIAS, C, XS, XF, M, N, GRP) \
        gemm256<KV, EPI><<<dim3((((M) + 255) / 256) * ((N) / 256)), dim3(512), 0, stream>>>( \
            A, W, BIAS, C, XS, XF, M, N, ((M) + 255) / 256, (N) / 256, GRP, \
            nullptr, nullptr, nullptr, 0, 0, 0, 0, 0x7fffffff)

    // ---- temporal branch: tqkv GEMM with W_comb folded in (dual problem)
    {
        int nm = (TROWS + 255) / 256, nn = (3 * DIM) / 256;   // 49 x 9 = 441
        int split = nm * nn;
        gemm256<DIM, EPI_STORE><<<dim3(split + 9), dim3(512), 0, stream>>>(
            bufA, w_tqkv, nullptr, bufB, nullptr, nullptr, TROWS, 3 * DIM, nm, nn, 1,
            w_tfc, tprojT, w_comb, DIM, DIM, 3, 3, split);
    }
    attn_temporal<<<dim3(TROWS * NH / 8 / 4), dim3(256), 0, stream>>>(bufB, bufC);
    GEMM256(DIM, EPI_INIT_TFC, bufC, w_comb, b_comb, nullptr, x, out, TROWS, DIM, 1);

    // ---- spatial attention ----
    ln_f32<<<dim3((MROWS + 3) / 4), dim3(256), 0, stream>>>(out, ln1_g, ln1_b, bufA, MROWS);
    GEMM256(DIM, EPI_STORE, bufA, w_qkv, nullptr, bufB, nullptr, nullptr, MROWS, 3 * DIM, 1);
    attn_spatial_mfma<<<dim3(BT_ * NH), dim3(256), 0, stream>>>(bufB, bufC);
    GEMM256(DIM, EPI_BIAS_ADD, bufC, w_proj, proj_b, nullptr, nullptr, out, MROWS, DIM, 1);

    // ---- MLP (padded HID' = 1280) ----
    ln_f32<<<dim3((MROWS + 3) / 4), dim3(256), 0, stream>>>(out, ln2_g, ln2_b, bufA, MROWS);
    GEMM256(DIM, EPI_BIAS_GELU, bufA, w_fc1p, fc1_bp, bufB, nullptr, nullptr, MROWS, HIDP, 1);
    GEMM256(HIDP, EPI_BIAS_ADD, bufB, w_fc2p, fc2_b, nullptr, nullptr, out, MROWS, DIM, 1);
    #undef GEMM256
}

// Round 15
// 375.203 us; speedup vs baseline: 1.2402x; 1.0022x over previous
//
#include <hip/hip_runtime.h>
#include <hip/hip_bf16.h>

// ---------------------------------------------------------------------------
// FactorizedAttentionBlock (TimeSformer divided space-time attention)
// DIM=768, NH=12, HD=64, HID=1152(pad 1280), B=8, T=8, HW=196, N=197, BT=64
// FP32 in/out. bf16 MFMA GEMMs + MFMA flash attention. fp32 residual in d_out.
// R15: R11/R14 base (verified best, 376.0us twice) + fc2 native K=1152 via
//      LD row-stride template param (skips the 2 zero K-tiles of the pad).
//      Everything else byte-identical to R14.
// ---------------------------------------------------------------------------

#define DIM   768
#define NH    12
#define HD    64
#define HID   1152
#define HIDP  1280
#define B_    8
#define T_    8
#define HW_   196
#define NTOK  197
#define BT_   64
#define MROWS (BT_ * NTOK)        // 12608
#define TROWS (B_ * HW_ * T_)     // 12544

typedef __bf16 bf16x8 __attribute__((ext_vector_type(8)));
typedef float  f32x4  __attribute__((ext_vector_type(4)));

__device__ inline float bf2f(ushort u) { return __uint_as_float(((unsigned)u) << 16); }
__device__ inline ushort f2bf(float f) {
    unsigned u = __float_as_uint(f);
    unsigned r = (u + 0x7fffu + ((u >> 16) & 1u)) >> 16;
    return (ushort)r;
}

__device__ inline float wred_sum(float v) {
    #pragma unroll
    for (int m = 32; m; m >>= 1) v += __shfl_xor(v, m);
    return v;
}

__device__ __forceinline__ void gload_lds16(const void* g, void* l) {
    __builtin_amdgcn_global_load_lds(
        (const __attribute__((address_space(1))) unsigned int*)g,
        (__attribute__((address_space(3))) unsigned int*)l, 16, 0, 0);
}

// XCD-bijective remap (m204)
__device__ __forceinline__ int xcd_lin(int gid, int nwg) {
    int q = nwg >> 3, r = nwg & 7;
    int xcd = gid & 7, idx = gid >> 3;
    return (xcd < r ? xcd * (q + 1) : r * (q + 1) + (xcd - r) * q) + idx;
}

#define MFMA16(a, b, c) __builtin_amdgcn_mfma_f32_16x16x32_bf16(a, b, c, 0, 0, 0)

// ---------------------------------------------------------------------------
// prep: single fused prep kernel, block-range dispatch.
// ---------------------------------------------------------------------------
#define PREP_T0 576
#define PREP_T1 (PREP_T0 + 192)
#define PREP_T2 (PREP_T1 + TROWS / 4)
#define FL_DD8  73728
#define FL_C0   (3 * FL_DD8)              // qkv
#define FL_C1   (FL_C0 + FL_DD8)          // proj
#define FL_C2   (FL_C1 + 3 * FL_DD8)      // tqkv
#define FL_C3   (FL_C2 + FL_DD8)          // tfc
#define FL_C4   (FL_C3 + HID * DIM / 8)   // fc1 rows
#define FL_C5   (FL_C4 + (HIDP - HID) * DIM / 8)  // fc1 pad rows
#define FL_C6   (FL_C5 + DIM * HIDP / 8)  // fc2 padded
#define FL_C7   (FL_C6 + HIDP / 8)        // fc1 bias pad
#define FL_C8   (FL_C7 + BT_ * DIM / 8)   // init_cls
#define PREP_GRID (PREP_T2 + (FL_C8 + 255) / 256)

__global__ __launch_bounds__(256) void prep(
    const float* __restrict__ x, const float* __restrict__ tln_g, const float* __restrict__ tln_b,
    const float* __restrict__ qkv_w, const float* __restrict__ proj_w,
    const float* __restrict__ tqkv_w, const float* __restrict__ tproj_w,
    const float* __restrict__ tproj_b, const float* __restrict__ tfc_wf,
    const float* __restrict__ tfc_b, const float* __restrict__ fc1_w,
    const float* __restrict__ fc1_b, const float* __restrict__ fc2_w,
    ushort* __restrict__ w_qkv, ushort* __restrict__ w_proj,
    ushort* __restrict__ w_tqkv, ushort* __restrict__ w_tfc,
    ushort* __restrict__ tprojT, ushort* __restrict__ w_fc1p,
    ushort* __restrict__ w_fc2p, float* __restrict__ fc1_bp,
    float* __restrict__ b_comb, ushort* __restrict__ bufA, float* __restrict__ out)
{
    __shared__ float tsm[32][33];
    int b = blockIdx.x, tid = threadIdx.x;

    if (b < PREP_T0) {             // ---- tproj transpose+cast
        int bx = b % 24, by = b / 24;
        int lx = tid & 31, ly = tid >> 5;
        #pragma unroll
        for (int i = 0; i < 32; i += 8)
            tsm[ly + i][lx] = tproj_w[(size_t)(by * 32 + ly + i) * DIM + bx * 32 + lx];
        __syncthreads();
        #pragma unroll
        for (int i = 0; i < 32; i += 8)
            tprojT[(size_t)(bx * 32 + ly + i) * DIM + by * 32 + lx] = f2bf(tsm[lx][ly + i]);
        return;
    }
    if (b < PREP_T1) {             // ---- b_comb
        int w = (b - PREP_T0) * 4 + (tid >> 6), lane = tid & 63;
        float s = 0.f;
        for (int j = lane; j < DIM; j += 64) s += tfc_wf[(size_t)w * DIM + j] * tproj_b[j];
        s = wred_sum(s);
        if (lane == 0) b_comb[w] = s + tfc_b[w];
        return;
    }
    if (b < PREP_T2) {             // ---- ln_gather -> bufA
        int widx = tid >> 6, lane = tid & 63;
        int r = (b - PREP_T1) * 4 + widx;
        int t = r & 7, pp = (r >> 3) % HW_, bb = r / (HW_ * T_);
        const float* row = x + ((size_t)(bb * T_ + t) * NTOK + 1 + pp) * DIM;
        float v[12], sum = 0.f, sq = 0.f;
        #pragma unroll
        for (int c = 0; c < 3; ++c) {
            float4 t4 = *(const float4*)(row + c * 256 + lane * 4);
            v[c*4+0] = t4.x; v[c*4+1] = t4.y; v[c*4+2] = t4.z; v[c*4+3] = t4.w;
            sum += t4.x + t4.y + t4.z + t4.w;
            sq  += t4.x*t4.x + t4.y*t4.y + t4.z*t4.z + t4.w*t4.w;
        }
        sum = wred_sum(sum); sq = wred_sum(sq);
        float mean = sum * (1.f / DIM);
        float var  = sq * (1.f / DIM) - mean * mean;
        float rstd = rsqrtf(var + 1e-5f);
        #pragma unroll
        for (int c = 0; c < 3; ++c) {
            int idx = c * 256 + lane * 4;
            float4 gg = *(const float4*)(tln_g + idx);
            float4 bb2 = *(const float4*)(tln_b + idx);
            ushort4 o;
            o.x = f2bf((v[c*4+0] - mean) * rstd * gg.x + bb2.x);
            o.y = f2bf((v[c*4+1] - mean) * rstd * gg.y + bb2.y);
            o.z = f2bf((v[c*4+2] - mean) * rstd * gg.z + bb2.z);
            o.w = f2bf((v[c*4+3] - mean) * rstd * gg.w + bb2.w);
            *(ushort4*)(bufA + (size_t)r * DIM + idx) = o;
        }
        return;
    }

    int i = (b - PREP_T2) * 256 + tid;
    if (i >= FL_C8) return;
    if (i < FL_C4) {
        const float* s; ushort* d; int base;
        if      (i < FL_C0) { s = qkv_w;  d = w_qkv;  base = 0;     }
        else if (i < FL_C1) { s = proj_w; d = w_proj; base = FL_C0; }
        else if (i < FL_C2) { s = tqkv_w; d = w_tqkv; base = FL_C1; }
        else if (i < FL_C3) { s = tfc_wf; d = w_tfc;  base = FL_C2; }
        else                { s = fc1_w;  d = w_fc1p; base = FL_C3; }
        int k = i - base;
        float4 a = *(const float4*)(s + (size_t)k * 8);
        float4 bb = *(const float4*)(s + (size_t)k * 8 + 4);
        ushort o[8] = {f2bf(a.x), f2bf(a.y), f2bf(a.z), f2bf(a.w),
                       f2bf(bb.x), f2bf(bb.y), f2bf(bb.z), f2bf(bb.w)};
        *(uint4*)(d + (size_t)k * 8) = *(const uint4*)o;
    } else if (i < FL_C5) {
        int k = i - FL_C4;
        uint4 z = {0u, 0u, 0u, 0u};
        *(uint4*)(w_fc1p + (size_t)HID * DIM + (size_t)k * 8) = z;
    } else if (i < FL_C6) {
        int k = i - FL_C5;
        int r = k / (HIDP / 8), c8 = (k % (HIDP / 8)) * 8;
        ushort o[8];
        if (c8 < HID) {
            const float* s = fc2_w + (size_t)r * HID + c8;
            #pragma unroll
            for (int e = 0; e < 8; ++e) o[e] = f2bf(s[e]);
        } else {
            #pragma unroll
            for (int e = 0; e < 8; ++e) o[e] = 0;
        }
        *(uint4*)(w_fc2p + (size_t)r * HIDP + c8) = *(const uint4*)o;
    } else if (i < FL_C7) {
        int k = (i - FL_C6) * 8;
        #pragma unroll
        for (int e = 0; e < 8; ++e) fc1_bp[k + e] = (k + e < HID) ? fc1_b[k + e] : 0.f;
    } else {
        int k = (i - FL_C7) * 8;
        int r = k / DIM, c = k % DIM;
        size_t off = (size_t)r * NTOK * DIM + c;
        *(float4*)(out + off)     = *(const float4*)(x + off);
        *(float4*)(out + off + 4) = *(const float4*)(x + off + 4);
    }
}

// ---------------------------------------------------------------------------
// gemm256 (R7/R11 schedule — empirical best): C[M,N] = A[M,KK] @ W[N,KK]^T
// with row stride LD (LD==KK except fc2: KK=1152 over LD=1280 buffers).
// 256x256 tile, 8 waves (2Mx4N), per-wave 128x64. BK=64, dbuf LDS (128KB),
// 4 phases/K-tile, one vmcnt(0)+barrier per K-tile, setprio on MFMA,
// XOR-swizzled LDS via pre-swizzled source. Dual-problem support: blocks
// >= split run problem 2 (used to fold W_comb into the tqkv dispatch).
// ---------------------------------------------------------------------------
enum { EPI_STORE = 0, EPI_BIAS_GELU = 1, EPI_BIAS_ADD = 2, EPI_INIT_TFC = 3 };

template <int KK, int LD, int EPI>
__global__ __launch_bounds__(512, 1) void gemm256(
    const ushort* __restrict__ Ag, const ushort* __restrict__ Wg,
    const float* __restrict__ bias, ushort* __restrict__ Cg,
    const float* __restrict__ xsrc, float* __restrict__ xf,
    int M, int N, int nm, int nn, int grp,
    const ushort* A2, const ushort* W2, ushort* C2,
    int M2, int N2, int nm2, int nn2, int split)
{
    __shared__ ushort As[2][256 * 64];
    __shared__ ushort Bs[2][256 * 64];

    const int tid  = threadIdx.x;
    const int lane = tid & 63, wid = tid >> 6;
    const int wr = wid >> 2, wc = wid & 3;
    const int fr = lane & 15, fq = lane >> 4;

    int bid = blockIdx.x;
    if (bid >= split) {            // problem 2 (W_comb)
        Ag = A2; Wg = W2; Cg = C2; M = M2; N = N2; nm = nm2; nn = nn2;
        bid -= split;
    }

    int lin = xcd_lin(bid, nm * nn);
    int per = grp * nn;
    int g2 = lin / per, rem = lin % per;
    int bm = g2 * grp;
    int gm = nm - bm; if (gm > grp) gm = grp;
    const int m0 = (bm + rem % gm) * 256;
    const int n0 = (rem / gm) * 256;

    const int srow = wid * 8 + (lane >> 3);
    const int scol = 8 * ((lane & 7) ^ (lane >> 3));
    const ushort* aP[4]; const ushort* bP[4];
    #pragma unroll
    for (int j = 0; j < 4; ++j) {
        int ra = m0 + j * 64 + srow; if (ra >= M) ra = M - 1;
        aP[j] = Ag + (size_t)ra * LD + scol;
        bP[j] = Wg + (size_t)(n0 + j * 64 + srow) * LD + scol;
    }
    const int ldso = (wid * 8) * 64;

    f32x4 acc[8][4] = {};
    bf16x8 af[4][2], b0[2][2], b1[2][2];

    const int sw0 = (fq * 8) ^ ((fr & 7) * 8);
    const int sw1 = (32 + fq * 8) ^ ((fr & 7) * 8);

    #pragma unroll
    for (int j = 0; j < 4; ++j) gload_lds16(aP[j], &As[0][j * 4096 + ldso]);
    #pragma unroll
    for (int j = 0; j < 4; ++j) gload_lds16(bP[j], &Bs[0][j * 4096 + ldso]);

    constexpr int NT = KK / 64;
    #pragma unroll
    for (int t = 0; t < NT; ++t) {
        const int rb = t & 1, wb = rb ^ 1;
        const bool st = (t + 1 < NT);
        const int kw = (t + 1) * 64;

        asm volatile("s_waitcnt vmcnt(0)" ::: "memory");
        __builtin_amdgcn_s_barrier();
        __builtin_amdgcn_sched_barrier(0);

        // ---- phase 0 ----
        #pragma unroll
        for (int mf = 0; mf < 4; ++mf) {
            af[mf][0] = *(const bf16x8*)&As[rb][(wr * 128 + mf * 16 + fr) * 64 + sw0];
            af[mf][1] = *(const bf16x8*)&As[rb][(wr * 128 + mf * 16 + fr) * 64 + sw1];
        }
        #pragma unroll
        for (int nf = 0; nf < 2; ++nf) {
            b0[nf][0] = *(const bf16x8*)&Bs[rb][(wc * 64 + nf * 16 + fr) * 64 + sw0];
            b0[nf][1] = *(const bf16x8*)&Bs[rb][(wc * 64 + nf * 16 + fr) * 64 + sw1];
        }
        if (st) {
            #pragma unroll
            for (int j = 0; j < 4; ++j) gload_lds16(aP[j] + kw, &As[wb][j * 4096 + ldso]);
        }
        asm volatile("s_waitcnt lgkmcnt(0)" ::: "memory");
        __builtin_amdgcn_sched_barrier(0);
        __builtin_amdgcn_s_setprio(1);
        #pragma unroll
        for (int mf = 0; mf < 4; ++mf)
            #pragma unroll
            for (int nf = 0; nf < 2; ++nf) {
                acc[mf][nf] = MFMA16(af[mf][0], b0[nf][0], acc[mf][nf]);
                acc[mf][nf] = MFMA16(af[mf][1], b0[nf][1], acc[mf][nf]);
            }
        __builtin_amdgcn_s_setprio(0);
        __builtin_amdgcn_sched_barrier(0);

        // ---- phase 1 ----
        #pragma unroll
        for (int nf = 0; nf < 2; ++nf) {
            b1[nf][0] = *(const bf16x8*)&Bs[rb][(wc * 64 + (nf + 2) * 16 + fr) * 64 + sw0];
            b1[nf][1] = *(const bf16x8*)&Bs[rb][(wc * 64 + (nf + 2) * 16 + fr) * 64 + sw1];
        }
        if (st) {
            #pragma unroll
            for (int j = 0; j < 4; ++j) gload_lds16(bP[j] + kw, &Bs[wb][j * 4096 + ldso]);
        }
        asm volatile("s_waitcnt lgkmcnt(0)" ::: "memory");
        __builtin_amdgcn_sched_barrier(0);
        __builtin_amdgcn_s_setprio(1);
        #pragma unroll
        for (int mf = 0; mf < 4; ++mf)
            #pragma unroll
            for (int nf = 0; nf < 2; ++nf) {
                acc[mf][nf + 2] = MFMA16(af[mf][0], b1[nf][0], acc[mf][nf + 2]);
                acc[mf][nf + 2] = MFMA16(af[mf][1], b1[nf][1], acc[mf][nf + 2]);
            }
        __builtin_amdgcn_s_setprio(0);
        __builtin_amdgcn_sched_barrier(0);

        // ---- phase 2 ----
        #pragma unroll
        for (int mf = 0; mf < 4; ++mf) {
            af[mf][0] = *(const bf16x8*)&As[rb][(wr * 128 + 64 + mf * 16 + fr) * 64 + sw0];
            af[mf][1] = *(const bf16x8*)&As[rb][(wr * 128 + 64 + mf * 16 + fr) * 64 + sw1];
        }
        asm volatile("s_waitcnt lgkmcnt(0)" ::: "memory");
        __builtin_amdgcn_sched_barrier(0);
        __builtin_amdgcn_s_setprio(1);
        #pragma unroll
        for (int mf = 0; mf < 4; ++mf)
            #pragma unroll
            for (int nf = 0; nf < 2; ++nf) {
                acc[mf + 4][nf] = MFMA16(af[mf][0], b0[nf][0], acc[mf + 4][nf]);
                acc[mf + 4][nf] = MFMA16(af[mf][1], b0[nf][1], acc[mf + 4][nf]);
            }
        __builtin_amdgcn_s_setprio(0);
        __builtin_amdgcn_sched_barrier(0);

        // ---- phase 3 ----
        __builtin_amdgcn_s_setprio(1);
        #pragma unroll
        for (int mf = 0; mf < 4; ++mf)
            #pragma unroll
            for (int nf = 0; nf < 2; ++nf) {
                acc[mf + 4][nf + 2] = MFMA16(af[mf][0], b1[nf][0], acc[mf + 4][nf + 2]);
                acc[mf + 4][nf + 2] = MFMA16(af[mf][1], b1[nf][1], acc[mf + 4][nf + 2]);
            }
        __builtin_amdgcn_s_setprio(0);
        __builtin_amdgcn_sched_barrier(0);
    }

    // epilogue: row = m0 + wr*128 + mf*16 + fq*4 + e; col = n0 + wc*64 + nf*16 + fr
    #pragma unroll
    for (int mf = 0; mf < 8; ++mf)
        #pragma unroll
        for (int e = 0; e < 4; ++e) {
            int row = m0 + wr * 128 + mf * 16 + fq * 4 + e;
            if (row >= M) continue;
            size_t dstrow = 0;
            if constexpr (EPI == EPI_INIT_TFC) {
                int t2 = row & 7, pp = (row >> 3) % HW_, bb = row / (HW_ * T_);
                dstrow = ((size_t)(bb * T_ + t2) * NTOK + 1 + pp) * DIM;
            }
            #pragma unroll
            for (int nf = 0; nf < 4; ++nf) {
                int col = n0 + wc * 64 + nf * 16 + fr;
                float v = acc[mf][nf][e];
                if constexpr (EPI != EPI_STORE) v += bias[col];
                if constexpr (EPI == EPI_BIAS_GELU) v = 0.5f * v * (1.0f + erff(v * 0.70710678118654752f));
                if constexpr (EPI == EPI_STORE || EPI == EPI_BIAS_GELU) {
                    Cg[(size_t)row * N + col] = f2bf(v);
                } else if constexpr (EPI == EPI_BIAS_ADD) {
                    xf[(size_t)row * DIM + col] += v;
                } else {
                    xf[dstrow + col] = xsrc[dstrow + col] + v;
                }
            }
        }
}

// ---------------------------------------------------------------------------
// LayerNorm fp32 src -> bf16 dst (768 wide, 1 wave/row)
// ---------------------------------------------------------------------------
__global__ __launch_bounds__(256) void ln_f32(
    const float* __restrict__ src, const float* __restrict__ g,
    const float* __restrict__ b, ushort* __restrict__ dst, int rows)
{
    int widx = threadIdx.x >> 6, lane = threadIdx.x & 63;
    int r = blockIdx.x * 4 + widx;
    if (r >= rows) return;
    const float* row = src + (size_t)r * DIM;
    float v[12], sum = 0.f, sq = 0.f;
    #pragma unroll
    for (int c = 0; c < 3; ++c) {
        float4 t = *(const float4*)(row + c * 256 + lane * 4);
        v[c*4+0] = t.x; v[c*4+1] = t.y; v[c*4+2] = t.z; v[c*4+3] = t.w;
        sum += t.x + t.y + t.z + t.w;
        sq  += t.x*t.x + t.y*t.y + t.z*t.z + t.w*t.w;
    }
    sum = wred_sum(sum); sq = wred_sum(sq);
    float mean = sum * (1.f / DIM);
    float var  = sq * (1.f / DIM) - mean * mean;
    float rstd = rsqrtf(var + 1e-5f);
    #pragma unroll
    for (int c = 0; c < 3; ++c) {
        int idx = c * 256 + lane * 4;
        float4 gg = *(const float4*)(g + idx);
        float4 bb = *(const float4*)(b + idx);
        ushort4 o;
        o.x = f2bf((v[c*4+0] - mean) * rstd * gg.x + bb.x);
        o.y = f2bf((v[c*4+1] - mean) * rstd * gg.y + bb.y);
        o.z = f2bf((v[c*4+2] - mean) * rstd * gg.z + bb.z);
        o.w = f2bf((v[c*4+3] - mean) * rstd * gg.w + bb.w);
        *(ushort4*)(dst + (size_t)r * DIM + idx) = o;
    }
}

// ---------------------------------------------------------------------------
// Temporal attention: seq len 8, one wave per (seq, head)
// ---------------------------------------------------------------------------
__global__ __launch_bounds__(256) void attn_temporal(
    const ushort* __restrict__ qkv, ushort* __restrict__ O)
{
    int widx = threadIdx.x >> 6, lane = threadIdx.x & 63;
    int w = blockIdx.x * 4 + widx;
    int s = w / NH, h = w % NH;
    int qi = lane >> 3, kj = lane & 7;

    const ushort* qrow = qkv + (size_t)(s * 8 + qi) * (3 * DIM) + h * HD;
    const ushort* krow = qkv + (size_t)(s * 8 + kj) * (3 * DIM) + DIM + h * HD;
    float d = 0.f;
    #pragma unroll
    for (int c = 0; c < 8; ++c) {
        uint4 qa = *(const uint4*)(qrow + c * 8);
        uint4 ka = *(const uint4*)(krow + c * 8);
        const ushort* qs = (const ushort*)&qa;
        const ushort* ks = (const ushort*)&ka;
        #pragma unroll
        for (int e = 0; e < 8; ++e) d += bf2f(qs[e]) * bf2f(ks[e]);
    }
    float sc = d * 0.125f;
    float mx = sc;
    #pragma unroll
    for (int m = 4; m; m >>= 1) mx = fmaxf(mx, __shfl_xor(mx, m));
    float p = expf(sc - mx);
    float sum = p;
    #pragma unroll
    for (int m = 4; m; m >>= 1) sum += __shfl_xor(sum, m);
    p /= sum;

    float o[8] = {};
    int base = lane & ~7;
    #pragma unroll
    for (int t = 0; t < 8; ++t) {
        float pt = __shfl(p, base + t);
        const ushort* vrow = qkv + (size_t)(s * 8 + t) * (3 * DIM) + 2 * DIM + h * HD + kj * 8;
        uint4 va = *(const uint4*)vrow;
        const ushort* vs = (const ushort*)&va;
        #pragma unroll
        for (int e = 0; e < 8; ++e) o[e] += pt * bf2f(vs[e]);
    }
    ushort out[8];
    #pragma unroll
    for (int e = 0; e < 8; ++e) out[e] = f2bf(o[e]);
    *(uint4*)(O + (size_t)(s * 8 + qi) * DIM + h * HD + kj * 8) = *(const uint4*)out;
}

// ---------------------------------------------------------------------------
// Spatial attention, MFMA. One block per (s,h); 4 waves; 768 blocks.
// ---------------------------------------------------------------------------
#define KS_STRIDE 72
#define VT_STRIDE 208
#define P_STRIDE  208
#define KS_OFF    0
#define VT_OFF    (197 * KS_STRIDE)
#define P_OFF     (VT_OFF + 64 * VT_STRIDE)
#define LDS_TOT   (P_OFF + 4 * 16 * P_STRIDE)

__global__ __launch_bounds__(256, 2) void attn_spatial_mfma(
    const ushort* __restrict__ qkv, ushort* __restrict__ O)
{
    __shared__ ushort lds[LDS_TOT];
    const int tid = threadIdx.x, lane = tid & 63, wid = tid >> 6;
    const int fr = lane & 15, fq = lane >> 4;
    int lin = xcd_lin(blockIdx.x, BT_ * NH);
    const int s = lin / NH, h = lin % NH;
    const size_t base = (size_t)s * NTOK * (3 * DIM);
    const ushort* Qg = qkv + base + h * HD;
    const ushort* Kg = qkv + base + DIM + h * HD;
    const ushort* Vg = qkv + base + 2 * DIM + h * HD;

    for (int chunk = tid; chunk < NTOK * 8; chunk += 256) {
        int r = chunk >> 3, c = (chunk & 7) * 8;
        uint4 v = *(const uint4*)(Kg + (size_t)r * (3 * DIM) + c);
        *(uint4*)&lds[KS_OFF + r * KS_STRIDE + c] = v;
    }
    for (int chunk = tid; chunk < 208 * 8; chunk += 256) {
        int k = chunk >> 3, c = (chunk & 7) * 8;
        uint4 v = {0u, 0u, 0u, 0u};
        if (k < NTOK) v = *(const uint4*)(Vg + (size_t)k * (3 * DIM) + c);
        const ushort* e = (const ushort*)&v;
        #pragma unroll
        for (int j = 0; j < 8; ++j) lds[VT_OFF + (c + j) * VT_STRIDE + k] = e[j];
    }
    __syncthreads();

    ushort* P = &lds[P_OFF + wid * 16 * P_STRIDE];

    for (int qi = wid; qi < 13; qi += 4) {
        int qrow = qi * 16 + fr; if (qrow > NTOK - 1) qrow = NTOK - 1;
        bf16x8 qf0 = *(const bf16x8*)(Qg + (size_t)qrow * (3 * DIM) + fq * 8);
        bf16x8 qf1 = *(const bf16x8*)(Qg + (size_t)qrow * (3 * DIM) + 32 + fq * 8);

        f32x4 sacc[13];
        #pragma unroll
        for (int t = 0; t < 13; ++t) {
            bf16x8 kf0 = *(const bf16x8*)&lds[KS_OFF + (t * 16 + fr) * KS_STRIDE + fq * 8];
            bf16x8 kf1 = *(const bf16x8*)&lds[KS_OFF + (t * 16 + fr) * KS_STRIDE + 32 + fq * 8];
            f32x4 z = {0.f, 0.f, 0.f, 0.f};
            z = MFMA16(kf0, qf0, z);
            sacc[t] = MFMA16(kf1, qf1, z);
        }

        float m = -1e30f;
        #pragma unroll
        for (int t = 0; t < 13; ++t)
            #pragma unroll
            for (int e = 0; e < 4; ++e) {
                int k = t * 16 + fq * 4 + e;
                float v = (k < NTOK) ? sacc[t][e] * 0.125f : -1e30f;
                sacc[t][e] = v;
                m = fmaxf(m, v);
            }
        m = fmaxf(m, __shfl_xor(m, 16));
        m = fmaxf(m, __shfl_xor(m, 32));
        float sum = 0.f;
        #pragma unroll
        for (int t = 0; t < 13; ++t)
            #pragma unroll
            for (int e = 0; e < 4; ++e) {
                float p = expf(sacc[t][e] - m);
                sacc[t][e] = p;
                sum += p;
            }
        sum += __shfl_xor(sum, 16);
        sum += __shfl_xor(sum, 32);
        float rd = 1.f / sum;

        #pragma unroll
        for (int t = 0; t < 13; ++t) {
            ushort2 w0 = { f2bf(sacc[t][0] * rd), f2bf(sacc[t][1] * rd) };
            ushort2 w1 = { f2bf(sacc[t][2] * rd), f2bf(sacc[t][3] * rd) };
            *(ushort2*)&P[fr * P_STRIDE + t * 16 + fq * 4]     = w0;
            *(ushort2*)&P[fr * P_STRIDE + t * 16 + fq * 4 + 2] = w1;
        }

        f32x4 oacc[4] = {};
        #pragma unroll
        for (int st = 0; st < 6; ++st) {
            bf16x8 pf = *(const bf16x8*)&P[fr * P_STRIDE + st * 32 + fq * 8];
            #pragma unroll
            for (int dt = 0; dt < 4; ++dt) {
                bf16x8 vf = *(const bf16x8*)&lds[VT_OFF + (dt * 16 + fr) * VT_STRIDE + st * 32 + fq * 8];
                oacc[dt] = MFMA16(pf, vf, oacc[dt]);
            }
        }
        {
            bf16x8 zz = {};
            bf16x8 pf = zz;
            if (fq < 2) pf = *(const bf16x8*)&P[fr * P_STRIDE + 192 + fq * 8];
            #pragma unroll
            for (int dt = 0; dt < 4; ++dt) {
                bf16x8 vf = zz;
                if (fq < 2) vf = *(const bf16x8*)&lds[VT_OFF + (dt * 16 + fr) * VT_STRIDE + 192 + fq * 8];
                oacc[dt] = MFMA16(pf, vf, oacc[dt]);
            }
        }

        #pragma unroll
        for (int dt = 0; dt < 4; ++dt)
            #pragma unroll
            for (int e = 0; e < 4; ++e) {
                int q = qi * 16 + fq * 4 + e;
                if (q < NTOK)
                    O[(size_t)(s * NTOK + q) * DIM + h * HD + dt * 16 + fr] = f2bf(oacc[dt][e]);
            }
    }
}

// ---------------------------------------------------------------------------
extern "C" void kernel_launch(void* const* d_in, const int* in_sizes, int n_in,
                              void* d_out, int out_size, void* d_ws, size_t ws_size,
                              hipStream_t stream)
{
    const float* x      = (const float*)d_in[0];
    const float* ln1_g  = (const float*)d_in[1];
    const float* ln1_b  = (const float*)d_in[2];
    const float* qkv_w  = (const float*)d_in[3];
    const float* proj_w = (const float*)d_in[4];
    const float* proj_b = (const float*)d_in[5];
    const float* tln_g  = (const float*)d_in[6];
    const float* tln_b  = (const float*)d_in[7];
    const float* tqkv_w = (const float*)d_in[8];
    const float* tproj_w= (const float*)d_in[9];
    const float* tproj_b= (const float*)d_in[10];
    const float* tfc_w  = (const float*)d_in[11];
    const float* tfc_b  = (const float*)d_in[12];
    const float* ln2_g  = (const float*)d_in[13];
    const float* ln2_b  = (const float*)d_in[14];
    const float* fc1_w  = (const float*)d_in[15];
    const float* fc1_b  = (const float*)d_in[16];
    const float* fc2_w  = (const float*)d_in[17];
    const float* fc2_b  = (const float*)d_in[18];

    float* out = (float*)d_out;   // fp32 residual accumulator = final output

    char* p = (char*)d_ws;
    ushort* w_qkv  = (ushort*)p; p += (size_t)(3*DIM*DIM) * 2;
    ushort* w_proj = (ushort*)p; p += (size_t)(DIM*DIM) * 2;
    ushort* w_tqkv = (ushort*)p; p += (size_t)(3*DIM*DIM) * 2;
    ushort* w_tfc  = (ushort*)p; p += (size_t)(DIM*DIM) * 2;
    ushort* tprojT = (ushort*)p; p += (size_t)(DIM*DIM) * 2;
    ushort* w_comb = (ushort*)p; p += (size_t)(DIM*DIM) * 2;
    ushort* w_fc1p = (ushort*)p; p += (size_t)(HIDP*DIM) * 2;
    ushort* w_fc2p = (ushort*)p; p += (size_t)(DIM*HIDP) * 2;
    float*  b_comb = (float*)p;  p += DIM * 4;
    float*  fc1_bp = (float*)p;  p += HIDP * 4;
    ushort* bufA   = (ushort*)p; p += (size_t)MROWS * DIM * 2;
    ushort* bufC   = (ushort*)p; p += (size_t)MROWS * DIM * 2;
    ushort* bufB   = (ushort*)p;  // MROWS*3*DIM bf16 (also holds [MROWS][1280])

    // ---- fused prep: transposes, casts, pads, b_comb, ln_gather, init_cls
    prep<<<dim3(PREP_GRID), dim3(256), 0, stream>>>(
        x, tln_g, tln_b, qkv_w, proj_w, tqkv_w, tproj_w, tproj_b,
        tfc_w, tfc_b, fc1_w, fc1_b, fc2_w,
        w_qkv, w_proj, w_tqkv, w_tfc, tprojT, w_fc1p, w_fc2p,
        fc1_bp, b_comb, bufA, out);

    #define GEMM256(KV, LDV, EPI, A, W, BIAS, C, XS, XF, M, N, GRP) \
        gemm256<KV, LDV, EPI><<<dim3((((M) + 255) / 256) * ((N) / 256)), dim3(512), 0, stream>>>( \
            A, W, BIAS, C, XS, XF, M, N, ((M) + 255) / 256, (N) / 256, GRP, \
            nullptr, nullptr, nullptr, 0, 0, 0, 0, 0x7fffffff)

    // ---- temporal branch: tqkv GEMM with W_comb folded in (dual problem)
    {
        int nm = (TROWS + 255) / 256, nn = (3 * DIM) / 256;   // 49 x 9 = 441
        int split = nm * nn;
        gemm256<DIM, DIM, EPI_STORE><<<dim3(split + 9), dim3(512), 0, stream>>>(
            bufA, w_tqkv, nullptr, bufB, nullptr, nullptr, TROWS, 3 * DIM, nm, nn, 1,
            w_tfc, tprojT, w_comb, DIM, DIM, 3, 3, split);
    }
    attn_temporal<<<dim3(TROWS * NH / 8 / 4), dim3(256), 0, stream>>>(bufB, bufC);
    GEMM256(DIM, DIM, EPI_INIT_TFC, bufC, w_comb, b_comb, nullptr, x, out, TROWS, DIM, 1);

    // ---- spatial attention ----
    ln_f32<<<dim3((MROWS + 3) / 4), dim3(256), 0, stream>>>(out, ln1_g, ln1_b, bufA, MROWS);
    GEMM256(DIM, DIM, EPI_STORE, bufA, w_qkv, nullptr, bufB, nullptr, nullptr, MROWS, 3 * DIM, 1);
    attn_spatial_mfma<<<dim3(BT_ * NH), dim3(256), 0, stream>>>(bufB, bufC);
    GEMM256(DIM, DIM, EPI_BIAS_ADD, bufC, w_proj, proj_b, nullptr, nullptr, out, MROWS, DIM, 1);

    // ---- MLP (fc1 N padded to 1280; fc2 native K=1152 over LD=1280 bufs) ----
    ln_f32<<<dim3((MROWS + 3) / 4), dim3(256), 0, stream>>>(out, ln2_g, ln2_b, bufA, MROWS);
    GEMM256(DIM, DIM, EPI_BIAS_GELU, bufA, w_fc1p, fc1_bp, bufB, nullptr, nullptr, MROWS, HIDP, 1);
    GEMM256(HID, HIDP, EPI_BIAS_ADD, bufB, w_fc2p, fc2_b, nullptr, nullptr, out, MROWS, DIM, 1);
    #undef GEMM256
}